// Round 10
// baseline (476.960 us; speedup 1.0000x reference)
//
#include <hip/hip_runtime.h>

#define N_NODES 20000
#define N_EDGES 320000
#define HID 64
#define MDIM 8
#define ROW 512            // HID*MDIM elements per node row (layout: [n][m][c])
#define NM 160000.0f       // N_NODES*MDIM
#define NCHUNK 79          // ceil(20000/256)
#define NSHADOW 16         // shadow copies per layer (BN stats)
#define POOLSH 256         // shadow copies for pooling (2.56M atomics -> ~312/line)
#define ZSTRIDE 72         // shorts per nm-row (64 + 8 pad)
#define ESRC_CAP 400000    // padded CSR capacity: 320000 + 20000*4 (pad to mult-of-4)

typedef unsigned int uint;
typedef unsigned char uchar;
typedef unsigned short ushort;
typedef __attribute__((ext_vector_type(8))) short bf16x8;
typedef __attribute__((ext_vector_type(4))) float f32x4;
typedef __attribute__((ext_vector_type(2))) float f32x2;

union U4B8 { uint4 u; bf16x8 b; };

__device__ __forceinline__ float bflo(uint u) { return __uint_as_float(u << 16); }
__device__ __forceinline__ float bfhi(uint u) { return __uint_as_float(u & 0xffff0000u); }
__device__ __forceinline__ uint f2bf(float f) {   // round-to-nearest-even
    uint u = __float_as_uint(f);
    return (u + 0x7fffu + ((u >> 16) & 1u)) >> 16;
}
__device__ __forceinline__ uint pack2(float lo, float hi) { return f2bf(lo) | (f2bf(hi) << 16); }
// pack 8 floats (from a bf16x8-packed uint4) into 8 fp8-e4m3 bytes
__device__ __forceinline__ uint2 pkfp8(uint4 pk) {
    int lo = 0, hi = 0;
    lo = __builtin_amdgcn_cvt_pk_fp8_f32(bflo(pk.x), bfhi(pk.x), lo, false);
    lo = __builtin_amdgcn_cvt_pk_fp8_f32(bflo(pk.y), bfhi(pk.y), lo, true);
    hi = __builtin_amdgcn_cvt_pk_fp8_f32(bflo(pk.z), bfhi(pk.z), hi, false);
    hi = __builtin_amdgcn_cvt_pk_fp8_f32(bflo(pk.w), bfhi(pk.w), hi, true);
    uint2 r; r.x = (uint)lo; r.y = (uint)hi; return r;
}

// ---------------- CSR build (padded to multiple-of-4 per node, pads point at SELF) ------------
// merged: edge histogram + weight pre-pack (independent index ranges, one dispatch)
__global__ __launch_bounds__(256) void k_histprep(const int* __restrict__ dst, int* __restrict__ deg,
                                                  const float* __restrict__ w1, const float* __restrict__ w2,
                                                  uint4* __restrict__ wfrag) {
    int id = blockIdx.x * 256 + threadIdx.x;
    if (id < N_EDGES) { atomicAdd(&deg[dst[id]], 1); return; }
    int pid = id - N_EDGES;                 // weight pre-pack: 4608 ids
    if (pid >= 4608) return;
    const float* W;
    int s;
    if (pid < 4096) {
        int layer = pid >> 10;          // 0..3 -> model layer layer+1
        int rem = pid & 1023;
        int which = rem >> 9;           // 0: w1, 1: w2
        s = rem & 511;
        W = which ? &w2[(size_t)(layer + 1) * 4096] : &w1[(size_t)layer * 4096];
    } else {
        s = pid - 4096;
        W = w2;                         // layer-0 w2
    }
    int f = s >> 6, l = s & 63;
    int o = (f >> 1) * 16 + (l & 15);
    int c0 = (f & 1) * 32 + (l >> 4) * 8;
    const float* p = &W[o * 64 + c0];
    uint4 a;
    a.x = pack2(p[0], p[1]); a.y = pack2(p[2], p[3]);
    a.z = pack2(p[4], p[5]); a.w = pack2(p[6], p[7]);
    wfrag[pid] = a;
}

__global__ __launch_bounds__(256) void k_csum(const int* __restrict__ deg, int* __restrict__ csum) {
    __shared__ int r[256];
    int t = threadIdx.x, i = blockIdx.x * 256 + t;
    r[t] = (i < N_NODES) ? ((deg[i] + 3) & ~3) : 0;
    __syncthreads();
    for (int s = 128; s > 0; s >>= 1) { if (t < s) r[t] += r[t + s]; __syncthreads(); }
    if (t == 0) csum[blockIdx.x] = r[0];
}

__global__ __launch_bounds__(128) void k_cscan(const int* __restrict__ csum, int* __restrict__ chunkoff) {
    __shared__ int s[128];
    int t = threadIdx.x;
    s[t] = (t < NCHUNK) ? csum[t] : 0;
    __syncthreads();
    if (t == 0) { int run = 0; for (int j = 0; j < NCHUNK; ++j) { int x = s[j]; s[j] = run; run += x; } }
    __syncthreads();
    if (t < NCHUNK) chunkoff[t] = s[t];
}

__global__ __launch_bounds__(256) void k_chunkscan(const int* __restrict__ deg, const int* __restrict__ chunkoff,
                                                   int* __restrict__ offs) {
    __shared__ int sd[256];
    int t = threadIdx.x, i = blockIdx.x * 256 + t;
    int v = (i < N_NODES) ? ((deg[i] + 3) & ~3) : 0;
    sd[t] = v;
    __syncthreads();
    for (int off = 1; off < 256; off <<= 1) {
        int x = (t >= off) ? sd[t - off] : 0;
        __syncthreads();
        sd[t] += x;
        __syncthreads();
    }
    if (i < N_NODES) offs[i] = sd[t] - v + chunkoff[blockIdx.x];
}

// merged: CSR fill (per-edge) + padding-slot fill (per-node x4, pads point at SELF node)
__global__ __launch_bounds__(256) void k_fillpad(const int* __restrict__ src, const int* __restrict__ dst,
                                                 const int* __restrict__ offs, const int* __restrict__ deg,
                                                 int* __restrict__ cursor, int* __restrict__ esrc) {
    int id = blockIdx.x * 256 + threadIdx.x;
    if (id < N_EDGES) {
        int d = dst[id];
        int p = atomicAdd(&cursor[d], 1);
        esrc[offs[d] + p] = src[id];
        return;
    }
    int pid = id - N_EDGES;                 // padding: N_NODES*4 ids
    if (pid >= N_NODES * 4) return;
    int n = pid >> 2, s = pid & 3;
    int dg = deg[n], pdg = (dg + 3) & ~3;
    int p = dg + s;
    if (p < pdg) esrc[offs[n] + p] = n;     // pad -> self; k_layer scales self by (1+dg-pdg)
}

// ---------------- fused layer 0 (MFMA): gather x (C=1) + rank-1 linear1 in B-frag regs + MFMA linear2
// block = 4 waves x 4 nodes; neighbor indices preloaded + shfl-broadcast (1 dependent load/round)
__global__ __launch_bounds__(256) void k_layer0(const float* __restrict__ x, const int* __restrict__ offs,
                                                const int* __restrict__ deg, const int* __restrict__ esrc,
                                                const float* __restrict__ W10, const float* __restrict__ B1,
                                                const uint4* __restrict__ w2f0, const float* __restrict__ B2,
                                                uchar* __restrict__ zout8, float* __restrict__ shadow) {
    __shared__ uint4 w2s[512];
    __shared__ __align__(16) ushort zbuf[128 * ZSTRIDE];
    int tid = threadIdx.x;
    for (int s2 = tid; s2 < 512; s2 += 256) w2s[s2] = w2f0[s2];
    __syncthreads();
    int w = tid >> 6, t = tid & 63;
    int n0 = blockIdx.x * 16 + w * 4;
    int g = t >> 3, m = t & 7;
    // ---- hoist per-node metadata + neighbor-index vectors (slots 0..63)
    int offv[4], dgv[4], idxv[4];
    #pragma unroll
    for (int i = 0; i < 4; ++i) { offv[i] = offs[n0 + i]; dgv[i] = deg[n0 + i]; }
    #pragma unroll
    for (int i = 0; i < 4; ++i) idxv[i] = (t < dgv[i]) ? esrc[offv[i] + t] : 0;
    // ---- gather zin0 for 4 nodes: 8 neighbor-slots x 8 m per round (idx via shfl) + xor-butterfly
    float zin0v[4];
    #pragma unroll
    for (int i = 0; i < 4; ++i) {
        int n = n0 + i;
        int dg = dgv[i];
        float acc = (t < 8) ? x[n * 8 + t] : 0.f;
        int dgc = dg < 64 ? dg : 64;
        for (int base = 0; base < dgc; base += 8) {
            int slot = base + g;
            int nb = __shfl(idxv[i], slot & 63);
            float v = 0.f;
            if (slot < dg) v = x[(size_t)nb * 8 + m];
            acc += v;
        }
        for (int k = 64 + g; k < dg; k += 8) {     // cold path (deg > 64: never for this data)
            int nb = esrc[offv[i] + k];
            acc += x[(size_t)nb * 8 + m];
        }
        acc += __shfl_xor(acc, 8);
        acc += __shfl_xor(acc, 16);
        acc += __shfl_xor(acc, 32);   // all lanes: zin0[node i][m = t&7]
        zin0v[i] = acc;
    }
    // ---- h = relu(w10*zin0 + b1) built directly in B-frag layout
    bf16x8 bfr[2][2];
    #pragma unroll
    for (int q2 = 0; q2 < 2; ++q2) {
        int kb = q2 * 32 + (t >> 4) * 8;
        float4 wA = *(const float4*)&W10[kb];
        float4 wB = *(const float4*)&W10[kb + 4];
        float4 bA = *(const float4*)&B1[kb];
        float4 bB = *(const float4*)&B1[kb + 4];
        #pragma unroll
        for (int tau = 0; tau < 2; ++tau) {
            float zv = zin0v[tau * 2 + ((t & 15) >> 3)];
            U4B8 u;
            u.u.x = pack2(fmaxf(fmaf(wA.x, zv, bA.x), 0.f), fmaxf(fmaf(wA.y, zv, bA.y), 0.f));
            u.u.y = pack2(fmaxf(fmaf(wA.z, zv, bA.z), 0.f), fmaxf(fmaf(wA.w, zv, bA.w), 0.f));
            u.u.z = pack2(fmaxf(fmaf(wB.x, zv, bB.x), 0.f), fmaxf(fmaf(wB.y, zv, bB.y), 0.f));
            u.u.w = pack2(fmaxf(fmaf(wB.z, zv, bB.z), 0.f), fmaxf(fmaf(wB.w, zv, bB.w), 0.f));
            bfr[q2][tau] = u.b;
        }
    }
    // ---- linear2 via MFMA
    f32x4 acc[4][2];
    #pragma unroll
    for (int o4 = 0; o4 < 4; ++o4) {
        float4 bv = *(const float4*)&B2[o4 * 16 + (t >> 4) * 4];
        #pragma unroll
        for (int tau = 0; tau < 2; ++tau) acc[o4][tau] = (f32x4){bv.x, bv.y, bv.z, bv.w};
    }
    #pragma unroll
    for (int o4 = 0; o4 < 4; ++o4)
        #pragma unroll
        for (int q2 = 0; q2 < 2; ++q2) {
            U4B8 a; a.u = w2s[(o4 * 2 + q2) * 64 + t];
            #pragma unroll
            for (int tau = 0; tau < 2; ++tau)
                acc[o4][tau] = __builtin_amdgcn_mfma_f32_16x16x32_bf16(a.b, bfr[q2][tau], acc[o4][tau], 0, 0, 0);
        }
    #pragma unroll
    for (int o4 = 0; o4 < 4; ++o4)
        #pragma unroll
        for (int tau = 0; tau < 2; ++tau) {
            acc[o4][tau][0] = fmaxf(acc[o4][tau][0], 0.f);
            acc[o4][tau][1] = fmaxf(acc[o4][tau][1], 0.f);
            acc[o4][tau][2] = fmaxf(acc[o4][tau][2], 0.f);
            acc[o4][tau][3] = fmaxf(acc[o4][tau][3], 0.f);
        }
    // BN stats
    int sid = (blockIdx.x & (NSHADOW - 1)) * 128;
    #pragma unroll
    for (int o4 = 0; o4 < 4; ++o4)
        #pragma unroll
        for (int r = 0; r < 4; ++r) {
            float x0 = acc[o4][0][r], x1 = acc[o4][1][r];
            float sv = x0 + x1;
            float ssv = x0 * x0 + x1 * x1;
            sv += __shfl_xor(sv, 1);  ssv += __shfl_xor(ssv, 1);
            sv += __shfl_xor(sv, 2);  ssv += __shfl_xor(ssv, 2);
            sv += __shfl_xor(sv, 4);  ssv += __shfl_xor(ssv, 4);
            sv += __shfl_xor(sv, 8);  ssv += __shfl_xor(ssv, 8);
            if ((t & 15) == o4 * 4 + r) {
                int ch = o4 * 16 + (t >> 4) * 4 + r;
                atomicAdd(&shadow[sid + ch], sv);
                atomicAdd(&shadow[sid + 64 + ch], ssv);
            }
        }
    // pack z into zbuf, coalesced fp8 uint2 stores
    #pragma unroll
    for (int o4 = 0; o4 < 4; ++o4)
        #pragma unroll
        for (int tau = 0; tau < 2; ++tau) {
            uint* p = (uint*)&zbuf[(w * 32 + tau * 16 + (t & 15)) * ZSTRIDE + o4 * 16 + (t >> 4) * 4];
            p[0] = pack2(acc[o4][tau][0], acc[o4][tau][1]);
            p[1] = pack2(acc[o4][tau][2], acc[o4][tau][3]);
        }
    #pragma unroll
    for (int i = 0; i < 4; ++i) {
        uint4 pk = *(const uint4*)&zbuf[(w * 32 + i * 8 + (t >> 3)) * ZSTRIDE + (t & 7) * 8];
        ((uint2*)(zout8 + (size_t)(n0 + i) * ROW))[t] = pkfp8(pk);
    }
}

// load a PAIR of neighbor rows with one wave instruction:
// lanes 0-31 -> row at idx[jj], lanes 32-63 -> row at idx[jj+1]; 16B per lane.
#define PAIRLD(rr, jj) do { \
    int nb_l = __builtin_amdgcn_readlane(idx, (jj)); \
    int nb_h = __builtin_amdgcn_readlane(idx, (jj) + 1); \
    int nb_ = hi ? nb_h : nb_l; \
    rr = ((const uint4*)(zprev8 + (size_t)nb_ * ROW))[q]; \
} while (0)

#define ACC16(rr) do { \
    f32x2 p_; \
    p_ = __builtin_amdgcn_cvt_pk_f32_fp8((int)rr.x, false); s0  += p_.x; s1  += p_.y; \
    p_ = __builtin_amdgcn_cvt_pk_f32_fp8((int)rr.x, true);  s2  += p_.x; s3  += p_.y; \
    p_ = __builtin_amdgcn_cvt_pk_f32_fp8((int)rr.y, false); s4  += p_.x; s5  += p_.y; \
    p_ = __builtin_amdgcn_cvt_pk_f32_fp8((int)rr.y, true);  s6  += p_.x; s7  += p_.y; \
    p_ = __builtin_amdgcn_cvt_pk_f32_fp8((int)rr.z, false); s8  += p_.x; s9  += p_.y; \
    p_ = __builtin_amdgcn_cvt_pk_f32_fp8((int)rr.z, true);  s10 += p_.x; s11 += p_.y; \
    p_ = __builtin_amdgcn_cvt_pk_f32_fp8((int)rr.w, false); s12 += p_.x; s13 += p_.y; \
    p_ = __builtin_amdgcn_cvt_pk_f32_fp8((int)rr.w, true);  s14 += p_.x; s15 += p_.y; \
} while (0)

// ---------------- fused layer (1..4): 1-wave block, 4 nodes; mult-4-padded gather (pads->self,
// self scaled by 1+dg-pdg); mixed 16/8/4-row rounds (up to 8 pair-loads in flight); MFMA MLP.
// last=1 (layer 4): skip z-store, accumulate pool sums directly from registers (k_pool fused away)
__global__ __launch_bounds__(64) __attribute__((amdgpu_waves_per_eu(2, 4)))
void k_layer(const uchar* __restrict__ zprev8,
             const float* __restrict__ shadow_prev,
             const float* __restrict__ gammaP, const float* __restrict__ betaP,
             const int* __restrict__ offs, const int* __restrict__ deg,
             const int* __restrict__ esrc,
             const uint4* __restrict__ w1f, const float* __restrict__ B1,
             const uint4* __restrict__ w2f, const float* __restrict__ B2,
             uchar* __restrict__ zout8, float* __restrict__ shadow,
             float* __restrict__ poolOut, int last) {
    __shared__ __align__(16) ushort zbuf[32 * ZSTRIDE];
    __shared__ __align__(16) float abl[128];
    int t = threadIdx.x;     // 0..63 (single wave)
    int n0 = blockIdx.x * 4;
    int q = t & 31;          // 16B chunk within row
    int hi = t >> 5;         // half-wave: 0 -> even row of pair, 1 -> odd
    // ---- hoist per-node metadata, neighbor-index vectors, self rows (one overlapped latency batch)
    int offv[4], dgv[4], pdgv[4], idxv[4];
    uint2 selfv[4];
    #pragma unroll
    for (int i = 0; i < 4; ++i) {
        offv[i] = offs[n0 + i];
        dgv[i] = deg[n0 + i];
        pdgv[i] = (dgv[i] + 3) & ~3;
    }
    #pragma unroll
    for (int i = 0; i < 4; ++i) idxv[i] = (t < pdgv[i]) ? esrc[offv[i] + t] : 0;
    #pragma unroll
    for (int i = 0; i < 4; ++i) selfv[i] = ((const uint2*)(zprev8 + (size_t)(n0 + i) * ROW))[q * 2 + hi];
    // ---- BN finalize of previous layer: one channel per thread
    {
        float s = 0.f, ss = 0.f;
        #pragma unroll
        for (int j = 0; j < NSHADOW; ++j) {
            s  += shadow_prev[j * 128 + t];
            ss += shadow_prev[j * 128 + 64 + t];
        }
        float mean = s * (1.f / NM);
        float var = ss * (1.f / NM) - mean * mean;
        float a = gammaP[t] * rsqrtf(var + 1e-5f);
        abl[t] = a;
        abl[64 + t] = betaP[t] - mean * a;
    }
    __syncthreads();
    const float4* abp = (const float4*)abl;
    // ---- gather 4 nodes: mixed rounds of 16/8/4 rows (8/4/2 pair-loads in flight)
    #pragma unroll
    for (int i = 0; i < 4; ++i) {
        int off = offv[i], dg = dgv[i], pdg = pdgv[i];
        float s0 = 0.f, s1 = 0.f, s2 = 0.f, s3 = 0.f, s4 = 0.f, s5 = 0.f, s6 = 0.f, s7 = 0.f;
        float s8 = 0.f, s9 = 0.f, s10 = 0.f, s11 = 0.f, s12 = 0.f, s13 = 0.f, s14 = 0.f, s15 = 0.f;
        for (int base = 0; base < pdg; base += 64) {
            int cnt = pdg - base; if (cnt > 64) cnt = 64;     // multiple of 4
            int idx = base ? ((t < cnt) ? esrc[off + base + t] : 0) : idxv[i];
            int j = 0;
            for (; j + 16 <= cnt; j += 16) {
                uint4 r0, r1, r2, r3, r4, r5, r6, r7;
                PAIRLD(r0, j);      PAIRLD(r1, j + 2);  PAIRLD(r2, j + 4);  PAIRLD(r3, j + 6);
                PAIRLD(r4, j + 8);  PAIRLD(r5, j + 10); PAIRLD(r6, j + 12); PAIRLD(r7, j + 14);
                ACC16(r0); ACC16(r1); ACC16(r2); ACC16(r3);
                ACC16(r4); ACC16(r5); ACC16(r6); ACC16(r7);
            }
            if (cnt - j >= 8) {
                uint4 r0, r1, r2, r3;
                PAIRLD(r0, j); PAIRLD(r1, j + 2); PAIRLD(r2, j + 4); PAIRLD(r3, j + 6);
                ACC16(r0); ACC16(r1); ACC16(r2); ACC16(r3);
                j += 8;
            }
            if (cnt - j >= 4) {
                uint4 r0, r1;
                PAIRLD(r0, j); PAIRLD(r1, j + 2);
                ACC16(r0); ACC16(r1);
            }
        }
        // combine half-wave partial sums: each lane keeps its 8 bytes (q*16 + hi*8 ..)
        float u, r0, r1, r2, r3, r4, r5, r6, r7;
        u = hi ? s0 : s8;   r0 = (hi ? s8  : s0) + __shfl_xor(u, 32);
        u = hi ? s1 : s9;   r1 = (hi ? s9  : s1) + __shfl_xor(u, 32);
        u = hi ? s2 : s10;  r2 = (hi ? s10 : s2) + __shfl_xor(u, 32);
        u = hi ? s3 : s11;  r3 = (hi ? s11 : s3) + __shfl_xor(u, 32);
        u = hi ? s4 : s12;  r4 = (hi ? s12 : s4) + __shfl_xor(u, 32);
        u = hi ? s5 : s13;  r5 = (hi ? s13 : s5) + __shfl_xor(u, 32);
        u = hi ? s6 : s14;  r6 = (hi ? s14 : s6) + __shfl_xor(u, 32);
        u = hi ? s7 : s15;  r7 = (hi ? s15 : s7) + __shfl_xor(u, 32);
        // self row: coefficient 1 + dg - pdg compensates the pad slots that point at self
        {
            uint2 sv = selfv[i];
            float cf = (float)(1 + dg - pdg);
            f32x2 p_;
            p_ = __builtin_amdgcn_cvt_pk_f32_fp8((int)sv.x, false); r0 = fmaf(cf, p_.x, r0); r1 = fmaf(cf, p_.y, r1);
            p_ = __builtin_amdgcn_cvt_pk_f32_fp8((int)sv.x, true);  r2 = fmaf(cf, p_.x, r2); r3 = fmaf(cf, p_.y, r3);
            p_ = __builtin_amdgcn_cvt_pk_f32_fp8((int)sv.y, false); r4 = fmaf(cf, p_.x, r4); r5 = fmaf(cf, p_.y, r5);
            p_ = __builtin_amdgcn_cvt_pk_f32_fp8((int)sv.y, true);  r6 = fmaf(cf, p_.x, r6); r7 = fmaf(cf, p_.y, r7);
        }
        // affine (folded BN of prev layer) + pack to zbuf
        int c4 = (q & 3) * 4 + hi * 2;          // float4 index: channel c0 = (q&3)*16 + hi*8
        float4 Af0 = abp[c4], Af1 = abp[c4 + 1];
        float4 Bf0 = abp[16 + c4], Bf1 = abp[16 + c4 + 1];
        float dp1 = (float)(dg + 1);
        uint4 pk;
        pk.x = pack2(fmaf(Af0.x, r0, Bf0.x * dp1), fmaf(Af0.y, r1, Bf0.y * dp1));
        pk.y = pack2(fmaf(Af0.z, r2, Bf0.z * dp1), fmaf(Af0.w, r3, Bf0.w * dp1));
        pk.z = pack2(fmaf(Af1.x, r4, Bf1.x * dp1), fmaf(Af1.y, r5, Bf1.y * dp1));
        pk.w = pack2(fmaf(Af1.z, r6, Bf1.z * dp1), fmaf(Af1.w, r7, Bf1.w * dp1));
        *(uint4*)&zbuf[(i * 8 + (q >> 2)) * ZSTRIDE + (q & 3) * 16 + hi * 8] = pk;
    }
    // ---- MLP via MFMA: D[64 o x 32 nm]; A-frags direct from global (L2-resident)
    bf16x8 bfr[2][2];
    #pragma unroll
    for (int tau = 0; tau < 2; ++tau)
        #pragma unroll
        for (int q2 = 0; q2 < 2; ++q2) {
            U4B8 u;
            u.u = *(const uint4*)&zbuf[(tau * 16 + (t & 15)) * ZSTRIDE + q2 * 32 + (t >> 4) * 8];
            bfr[q2][tau] = u.b;
        }
    f32x4 acc[4][2];
    #pragma unroll
    for (int o4 = 0; o4 < 4; ++o4) {
        float4 bv = *(const float4*)&B1[o4 * 16 + (t >> 4) * 4];
        #pragma unroll
        for (int tau = 0; tau < 2; ++tau) acc[o4][tau] = (f32x4){bv.x, bv.y, bv.z, bv.w};
    }
    #pragma unroll
    for (int o4 = 0; o4 < 4; ++o4)
        #pragma unroll
        for (int q2 = 0; q2 < 2; ++q2) {
            U4B8 a; a.u = w1f[(o4 * 2 + q2) * 64 + t];
            #pragma unroll
            for (int tau = 0; tau < 2; ++tau)
                acc[o4][tau] = __builtin_amdgcn_mfma_f32_16x16x32_bf16(a.b, bfr[q2][tau], acc[o4][tau], 0, 0, 0);
        }
    #pragma unroll
    for (int o4 = 0; o4 < 4; ++o4)
        #pragma unroll
        for (int tau = 0; tau < 2; ++tau) {
            f32x4 v = acc[o4][tau];
            float h0 = fmaxf(v[0], 0.f), h1 = fmaxf(v[1], 0.f), h2 = fmaxf(v[2], 0.f), h3 = fmaxf(v[3], 0.f);
            uint* p = (uint*)&zbuf[(tau * 16 + (t & 15)) * ZSTRIDE + o4 * 16 + (t >> 4) * 4];
            p[0] = pack2(h0, h1); p[1] = pack2(h2, h3);
        }
    #pragma unroll
    for (int tau = 0; tau < 2; ++tau)
        #pragma unroll
        for (int q2 = 0; q2 < 2; ++q2) {
            U4B8 u;
            u.u = *(const uint4*)&zbuf[(tau * 16 + (t & 15)) * ZSTRIDE + q2 * 32 + (t >> 4) * 8];
            bfr[q2][tau] = u.b;
        }
    #pragma unroll
    for (int o4 = 0; o4 < 4; ++o4) {
        float4 bv = *(const float4*)&B2[o4 * 16 + (t >> 4) * 4];
        #pragma unroll
        for (int tau = 0; tau < 2; ++tau) acc[o4][tau] = (f32x4){bv.x, bv.y, bv.z, bv.w};
    }
    #pragma unroll
    for (int o4 = 0; o4 < 4; ++o4)
        #pragma unroll
        for (int q2 = 0; q2 < 2; ++q2) {
            U4B8 a; a.u = w2f[(o4 * 2 + q2) * 64 + t];
            #pragma unroll
            for (int tau = 0; tau < 2; ++tau)
                acc[o4][tau] = __builtin_amdgcn_mfma_f32_16x16x32_bf16(a.b, bfr[q2][tau], acc[o4][tau], 0, 0, 0);
        }
    #pragma unroll
    for (int o4 = 0; o4 < 4; ++o4)
        #pragma unroll
        for (int tau = 0; tau < 2; ++tau) {
            acc[o4][tau][0] = fmaxf(acc[o4][tau][0], 0.f);
            acc[o4][tau][1] = fmaxf(acc[o4][tau][1], 0.f);
            acc[o4][tau][2] = fmaxf(acc[o4][tau][2], 0.f);
            acc[o4][tau][3] = fmaxf(acc[o4][tau][3], 0.f);
        }
    // BN stats: butterfly over 16-lane column group, 2 predicated atomics per matching lane
    int sid = (blockIdx.x & (NSHADOW - 1)) * 128;
    #pragma unroll
    for (int o4 = 0; o4 < 4; ++o4)
        #pragma unroll
        for (int r = 0; r < 4; ++r) {
            float x0 = acc[o4][0][r], x1 = acc[o4][1][r];
            float sv = x0 + x1;
            float ssv = x0 * x0 + x1 * x1;
            sv += __shfl_xor(sv, 1);  ssv += __shfl_xor(ssv, 1);
            sv += __shfl_xor(sv, 2);  ssv += __shfl_xor(ssv, 2);
            sv += __shfl_xor(sv, 4);  ssv += __shfl_xor(ssv, 4);
            sv += __shfl_xor(sv, 8);  ssv += __shfl_xor(ssv, 8);
            if ((t & 15) == o4 * 4 + r) {
                int ch = o4 * 16 + (t >> 4) * 4 + r;
                atomicAdd(&shadow[sid + ch], sv);
                atomicAdd(&shadow[sid + 64 + ch], ssv);
            }
        }
    if (last) {
        // ---- fused pooling: sum over this block's 4 nodes per (m,c); raw z (pre-BN) like k_pool did.
        // acc[o4][tau][r] = z[node = tau*2 + ((t&15)>>3)][m = t&7][c = o4*16 + (t>>4)*4 + r]
        // POOLSH=256 shadow copies: 2.56M atomics spread over 2048 cachelines (~312/line)
        int sidp = (blockIdx.x & (POOLSH - 1)) * 512;
        #pragma unroll
        for (int o4 = 0; o4 < 4; ++o4)
            #pragma unroll
            for (int r = 0; r < 4; ++r) {
                float v = acc[o4][0][r] + acc[o4][1][r];   // sum over tau (2 nodes)
                v += __shfl_xor(v, 8);                     // sum over lane-bit-3 (other 2 nodes)
                if ((t & 8) == 0) {
                    int c = o4 * 16 + (t >> 4) * 4 + r;
                    atomicAdd(&poolOut[sidp + (t & 7) * 64 + c], v);
                }
            }
    } else {
        // pack z2 into zbuf, then coalesced fp8 stores per node
        #pragma unroll
        for (int o4 = 0; o4 < 4; ++o4)
            #pragma unroll
            for (int tau = 0; tau < 2; ++tau) {
                uint* p = (uint*)&zbuf[(tau * 16 + (t & 15)) * ZSTRIDE + o4 * 16 + (t >> 4) * 4];
                p[0] = pack2(acc[o4][tau][0], acc[o4][tau][1]);
                p[1] = pack2(acc[o4][tau][2], acc[o4][tau][3]);
            }
        #pragma unroll
        for (int i = 0; i < 4; ++i) {
            uint4 pk = *(const uint4*)&zbuf[(i * 8 + (t >> 3)) * ZSTRIDE + (t & 7) * 8];
            ((uint2*)(zout8 + (size_t)(n0 + i) * ROW))[t] = pkfp8(pk);
        }
    }
}

// ---------------- head: fold layer-4 BN finalize + pool-normalize + linear + sigmoid
__global__ __launch_bounds__(64) void k_out(const float* __restrict__ pool, const float* __restrict__ shadow4,
                                            const float* __restrict__ gamma4, const float* __restrict__ beta4,
                                            const float* __restrict__ wout, const float* __restrict__ bout,
                                            float* __restrict__ out) {
    int c = threadIdx.x;
    float s = 0.f, ss = 0.f;
    #pragma unroll
    for (int j = 0; j < NSHADOW; ++j) { s += shadow4[j * 128 + c]; ss += shadow4[j * 128 + 64 + c]; }
    float mean = s * (1.f / NM);
    float var = ss * (1.f / NM) - mean * mean;
    float a = gamma4[c] * rsqrtf(var + 1e-5f);
    float b = beta4[c] - mean * a;
    float wv = wout[c];
    for (int m = 0; m < 8; ++m) {
        float pv0 = 0.f, pv1 = 0.f, pv2 = 0.f, pv3 = 0.f;
        #pragma unroll 4
        for (int j = 0; j < POOLSH; j += 4) {
            pv0 += pool[(j + 0) * 512 + m * 64 + c];
            pv1 += pool[(j + 1) * 512 + m * 64 + c];
            pv2 += pool[(j + 2) * 512 + m * 64 + c];
            pv3 += pool[(j + 3) * 512 + m * 64 + c];
        }
        float pv = (pv0 + pv1) + (pv2 + pv3);
        float v = wv * (a * pv * (1.f / N_NODES) + b);
        for (int off = 32; off > 0; off >>= 1) v += __shfl_down(v, off);
        if (c == 0) out[m] = 1.f / (1.f + expf(-(v + bout[0])));
    }
}

extern "C" void kernel_launch(void* const* d_in, const int* in_sizes, int n_in,
                              void* d_out, int out_size, void* d_ws, size_t ws_size,
                              hipStream_t stream) {
    const float* x     = (const float*)d_in[0];
    const int*   ei    = (const int*)d_in[1];
    const int*   srcp  = ei;
    const int*   dstp  = ei + N_EDGES;
    const float* w1_0  = (const float*)d_in[3];
    const float* w1    = (const float*)d_in[4];   // [4][64][64]
    const float* b1    = (const float*)d_in[5];   // [5][64]
    const float* w2    = (const float*)d_in[6];   // [5][64][64]
    const float* b2    = (const float*)d_in[7];
    const float* gamma = (const float*)d_in[8];
    const float* beta  = (const float*)d_in[9];
    const float* wout  = (const float*)d_in[10];
    const float* bout  = (const float*)d_in[11];
    float* out = (float*)d_out;

    char* ws = (char*)d_ws;
    size_t off = 0;
    auto alloc = [&](size_t bytes) -> void* {
        void* p = ws + off;
        off = (off + bytes + 255) & ~(size_t)255;
        return p;
    };
    uchar* zA8   = (uchar*)alloc((size_t)N_NODES * ROW);        // 10.25 MB fp8
    uchar* zB8   = (uchar*)alloc((size_t)N_NODES * ROW);
    uint4* wfrag = (uint4*)alloc(4608 * 16);                    // pre-packed A-fragments
    // ---- contiguous zero-initialized span: deg, cursor, shadow[5], pool (POOLSH copies)
    int* deg      = (int*)alloc(N_NODES * 4);
    int* cursor   = (int*)alloc(N_NODES * 4);
    float* shadow = (float*)alloc(5 * NSHADOW * 128 * 4);
    float* pool   = (float*)alloc(POOLSH * 512 * 4);            // 512 KB
    size_t zero_bytes = (size_t)((char*)pool - (char*)deg) + POOLSH * 512 * 4;
    // ---- uninitialized scratch
    int* offs     = (int*)alloc(N_NODES * 4);
    int* esrc     = (int*)alloc(ESRC_CAP * 4);
    int* csum     = (int*)alloc(NCHUNK * 4);
    int* chunkoff = (int*)alloc(NCHUNK * 4);

    hipMemsetAsync(deg, 0, zero_bytes, stream);

    // CSR build (padded, pads->self) + weight pre-pack; merged dispatches
    k_histprep<<<(N_EDGES + 4608 + 255) / 256, 256, 0, stream>>>(dstp, deg, w1, w2, wfrag);
    k_csum<<<NCHUNK, 256, 0, stream>>>(deg, csum);
    k_cscan<<<1, 128, 0, stream>>>(csum, chunkoff);
    k_chunkscan<<<NCHUNK, 256, 0, stream>>>(deg, chunkoff, offs);
    k_fillpad<<<(N_EDGES + N_NODES * 4 + 255) / 256, 256, 0, stream>>>(srcp, dstp, offs, deg, cursor, esrc);

    // layer 0 (MFMA, fp8 output)
    k_layer0<<<N_NODES / 16, 256, 0, stream>>>(x, offs, deg, esrc, w1_0, b1, wfrag + 4096, b2,
                                               zA8, shadow);

    // layers 1..4 fused; ping-pong zA8 <-> zB8 (1-wave blocks, 4 nodes each);
    // layer 4 skips z-store and accumulates pool directly (k_pool fused away)
    const uchar* zin8 = zA8;
    uchar* zo8 = zB8;
    for (int i = 1; i <= 4; ++i) {
        k_layer<<<N_NODES / 4, 64, 0, stream>>>(zin8,
                                                shadow + (size_t)(i - 1) * NSHADOW * 128,
                                                gamma + (i - 1) * 64, beta + (i - 1) * 64,
                                                offs, deg, esrc,
                                                wfrag + (size_t)(i - 1) * 1024, b1 + i * 64,
                                                wfrag + (size_t)(i - 1) * 1024 + 512, b2 + i * 64,
                                                zo8,
                                                shadow + (size_t)i * NSHADOW * 128,
                                                pool, (i == 4) ? 1 : 0);
        const uchar* t8 = zin8; zin8 = zo8; zo8 = (uchar*)t8;
    }

    // head
    k_out<<<1, 64, 0, stream>>>(pool, shadow + 4 * NSHADOW * 128, gamma + 256, beta + 256, wout, bout, out);
}

// Round 11
// 406.575 us; speedup vs baseline: 1.1731x; 1.1731x over previous
//
#include <hip/hip_runtime.h>

#define N_NODES 20000
#define N_EDGES 320000
#define HID 64
#define MDIM 8
#define ROW 512            // HID*MDIM elements per node row (layout: [n][m][c])
#define NM 160000.0f       // N_NODES*MDIM
#define NCHUNK 79          // ceil(20000/256)
#define NSHADOW 16         // shadow copies per layer (BN stats)
#define POOLSH 256         // shadow copies for pooling (2.56M atomics -> ~312/line)
#define ZSTRIDE 72         // shorts per nm-row (64 + 8 pad)
#define ESRC_CAP 400000    // padded CSR capacity: 320000 + 20000*4 (pad to mult-of-4)

typedef unsigned int uint;
typedef unsigned char uchar;
typedef unsigned short ushort;
typedef __attribute__((ext_vector_type(8))) short bf16x8;
typedef __attribute__((ext_vector_type(4))) float f32x4;
typedef __attribute__((ext_vector_type(2))) float f32x2;

union U4B8 { uint4 u; bf16x8 b; };

__device__ __forceinline__ float bflo(uint u) { return __uint_as_float(u << 16); }
__device__ __forceinline__ float bfhi(uint u) { return __uint_as_float(u & 0xffff0000u); }
__device__ __forceinline__ uint f2bf(float f) {   // round-to-nearest-even
    uint u = __float_as_uint(f);
    return (u + 0x7fffu + ((u >> 16) & 1u)) >> 16;
}
__device__ __forceinline__ uint pack2(float lo, float hi) { return f2bf(lo) | (f2bf(hi) << 16); }
// pack 8 floats (from a bf16x8-packed uint4) into 8 fp8-e4m3 bytes
__device__ __forceinline__ uint2 pkfp8(uint4 pk) {
    int lo = 0, hi = 0;
    lo = __builtin_amdgcn_cvt_pk_fp8_f32(bflo(pk.x), bfhi(pk.x), lo, false);
    lo = __builtin_amdgcn_cvt_pk_fp8_f32(bflo(pk.y), bfhi(pk.y), lo, true);
    hi = __builtin_amdgcn_cvt_pk_fp8_f32(bflo(pk.z), bfhi(pk.z), hi, false);
    hi = __builtin_amdgcn_cvt_pk_fp8_f32(bflo(pk.w), bfhi(pk.w), hi, true);
    uint2 r; r.x = (uint)lo; r.y = (uint)hi; return r;
}

// ---------------- CSR build (padded to multiple-of-4 per node, pads point at SELF) ------------
// merged: edge histogram + weight pre-pack (independent index ranges, one dispatch)
__global__ __launch_bounds__(256) void k_histprep(const int* __restrict__ dst, int* __restrict__ deg,
                                                  const float* __restrict__ w1, const float* __restrict__ w2,
                                                  uint4* __restrict__ wfrag) {
    int id = blockIdx.x * 256 + threadIdx.x;
    if (id < N_EDGES) { atomicAdd(&deg[dst[id]], 1); return; }
    int pid = id - N_EDGES;                 // weight pre-pack: 4608 ids
    if (pid >= 4608) return;
    const float* W;
    int s;
    if (pid < 4096) {
        int layer = pid >> 10;          // 0..3 -> model layer layer+1
        int rem = pid & 1023;
        int which = rem >> 9;           // 0: w1, 1: w2
        s = rem & 511;
        W = which ? &w2[(size_t)(layer + 1) * 4096] : &w1[(size_t)layer * 4096];
    } else {
        s = pid - 4096;
        W = w2;                         // layer-0 w2
    }
    int f = s >> 6, l = s & 63;
    int o = (f >> 1) * 16 + (l & 15);
    int c0 = (f & 1) * 32 + (l >> 4) * 8;
    const float* p = &W[o * 64 + c0];
    uint4 a;
    a.x = pack2(p[0], p[1]); a.y = pack2(p[2], p[3]);
    a.z = pack2(p[4], p[5]); a.w = pack2(p[6], p[7]);
    wfrag[pid] = a;
}

__global__ __launch_bounds__(256) void k_csum(const int* __restrict__ deg, int* __restrict__ csum) {
    __shared__ int r[256];
    int t = threadIdx.x, i = blockIdx.x * 256 + t;
    r[t] = (i < N_NODES) ? ((deg[i] + 3) & ~3) : 0;
    __syncthreads();
    for (int s = 128; s > 0; s >>= 1) { if (t < s) r[t] += r[t + s]; __syncthreads(); }
    if (t == 0) csum[blockIdx.x] = r[0];
}

__global__ __launch_bounds__(128) void k_cscan(const int* __restrict__ csum, int* __restrict__ chunkoff) {
    __shared__ int s[128];
    int t = threadIdx.x;
    s[t] = (t < NCHUNK) ? csum[t] : 0;
    __syncthreads();
    if (t == 0) { int run = 0; for (int j = 0; j < NCHUNK; ++j) { int x = s[j]; s[j] = run; run += x; } }
    __syncthreads();
    if (t < NCHUNK) chunkoff[t] = s[t];
}

__global__ __launch_bounds__(256) void k_chunkscan(const int* __restrict__ deg, const int* __restrict__ chunkoff,
                                                   int* __restrict__ offs) {
    __shared__ int sd[256];
    int t = threadIdx.x, i = blockIdx.x * 256 + t;
    int v = (i < N_NODES) ? ((deg[i] + 3) & ~3) : 0;
    sd[t] = v;
    __syncthreads();
    for (int off = 1; off < 256; off <<= 1) {
        int x = (t >= off) ? sd[t - off] : 0;
        __syncthreads();
        sd[t] += x;
        __syncthreads();
    }
    if (i < N_NODES) offs[i] = sd[t] - v + chunkoff[blockIdx.x];
}

// merged: CSR fill (per-edge) + padding-slot fill (per-node x4, pads point at SELF node)
__global__ __launch_bounds__(256) void k_fillpad(const int* __restrict__ src, const int* __restrict__ dst,
                                                 const int* __restrict__ offs, const int* __restrict__ deg,
                                                 int* __restrict__ cursor, int* __restrict__ esrc) {
    int id = blockIdx.x * 256 + threadIdx.x;
    if (id < N_EDGES) {
        int d = dst[id];
        int p = atomicAdd(&cursor[d], 1);
        esrc[offs[d] + p] = src[id];
        return;
    }
    int pid = id - N_EDGES;                 // padding: N_NODES*4 ids
    if (pid >= N_NODES * 4) return;
    int n = pid >> 2, s = pid & 3;
    int dg = deg[n], pdg = (dg + 3) & ~3;
    int p = dg + s;
    if (p < pdg) esrc[offs[n] + p] = n;     // pad -> self; k_layer scales self by (1+dg-pdg)
}

// ---------------- fused layer 0 (MFMA): gather x (C=1) + rank-1 linear1 in B-frag regs + MFMA linear2
// block = 4 waves x 4 nodes; neighbor indices preloaded + shfl-broadcast (1 dependent load/round)
__global__ __launch_bounds__(256) void k_layer0(const float* __restrict__ x, const int* __restrict__ offs,
                                                const int* __restrict__ deg, const int* __restrict__ esrc,
                                                const float* __restrict__ W10, const float* __restrict__ B1,
                                                const uint4* __restrict__ w2f0, const float* __restrict__ B2,
                                                uchar* __restrict__ zout8, float* __restrict__ shadow) {
    __shared__ uint4 w2s[512];
    __shared__ __align__(16) ushort zbuf[128 * ZSTRIDE];
    int tid = threadIdx.x;
    for (int s2 = tid; s2 < 512; s2 += 256) w2s[s2] = w2f0[s2];
    __syncthreads();
    int w = tid >> 6, t = tid & 63;
    int n0 = blockIdx.x * 16 + w * 4;
    int g = t >> 3, m = t & 7;
    // ---- hoist per-node metadata + neighbor-index vectors (slots 0..63)
    int offv[4], dgv[4], idxv[4];
    #pragma unroll
    for (int i = 0; i < 4; ++i) { offv[i] = offs[n0 + i]; dgv[i] = deg[n0 + i]; }
    #pragma unroll
    for (int i = 0; i < 4; ++i) idxv[i] = (t < dgv[i]) ? esrc[offv[i] + t] : 0;
    // ---- gather zin0 for 4 nodes: 8 neighbor-slots x 8 m per round (idx via shfl) + xor-butterfly
    float zin0v[4];
    #pragma unroll
    for (int i = 0; i < 4; ++i) {
        int n = n0 + i;
        int dg = dgv[i];
        float acc = (t < 8) ? x[n * 8 + t] : 0.f;
        int dgc = dg < 64 ? dg : 64;
        for (int base = 0; base < dgc; base += 8) {
            int slot = base + g;
            int nb = __shfl(idxv[i], slot & 63);
            float v = 0.f;
            if (slot < dg) v = x[(size_t)nb * 8 + m];
            acc += v;
        }
        for (int k = 64 + g; k < dg; k += 8) {     // cold path (deg > 64: never for this data)
            int nb = esrc[offv[i] + k];
            acc += x[(size_t)nb * 8 + m];
        }
        acc += __shfl_xor(acc, 8);
        acc += __shfl_xor(acc, 16);
        acc += __shfl_xor(acc, 32);   // all lanes: zin0[node i][m = t&7]
        zin0v[i] = acc;
    }
    // ---- h = relu(w10*zin0 + b1) built directly in B-frag layout
    bf16x8 bfr[2][2];
    #pragma unroll
    for (int q2 = 0; q2 < 2; ++q2) {
        int kb = q2 * 32 + (t >> 4) * 8;
        float4 wA = *(const float4*)&W10[kb];
        float4 wB = *(const float4*)&W10[kb + 4];
        float4 bA = *(const float4*)&B1[kb];
        float4 bB = *(const float4*)&B1[kb + 4];
        #pragma unroll
        for (int tau = 0; tau < 2; ++tau) {
            float zv = zin0v[tau * 2 + ((t & 15) >> 3)];
            U4B8 u;
            u.u.x = pack2(fmaxf(fmaf(wA.x, zv, bA.x), 0.f), fmaxf(fmaf(wA.y, zv, bA.y), 0.f));
            u.u.y = pack2(fmaxf(fmaf(wA.z, zv, bA.z), 0.f), fmaxf(fmaf(wA.w, zv, bA.w), 0.f));
            u.u.z = pack2(fmaxf(fmaf(wB.x, zv, bB.x), 0.f), fmaxf(fmaf(wB.y, zv, bB.y), 0.f));
            u.u.w = pack2(fmaxf(fmaf(wB.z, zv, bB.z), 0.f), fmaxf(fmaf(wB.w, zv, bB.w), 0.f));
            bfr[q2][tau] = u.b;
        }
    }
    // ---- linear2 via MFMA
    f32x4 acc[4][2];
    #pragma unroll
    for (int o4 = 0; o4 < 4; ++o4) {
        float4 bv = *(const float4*)&B2[o4 * 16 + (t >> 4) * 4];
        #pragma unroll
        for (int tau = 0; tau < 2; ++tau) acc[o4][tau] = (f32x4){bv.x, bv.y, bv.z, bv.w};
    }
    #pragma unroll
    for (int o4 = 0; o4 < 4; ++o4)
        #pragma unroll
        for (int q2 = 0; q2 < 2; ++q2) {
            U4B8 a; a.u = w2s[(o4 * 2 + q2) * 64 + t];
            #pragma unroll
            for (int tau = 0; tau < 2; ++tau)
                acc[o4][tau] = __builtin_amdgcn_mfma_f32_16x16x32_bf16(a.b, bfr[q2][tau], acc[o4][tau], 0, 0, 0);
        }
    #pragma unroll
    for (int o4 = 0; o4 < 4; ++o4)
        #pragma unroll
        for (int tau = 0; tau < 2; ++tau) {
            acc[o4][tau][0] = fmaxf(acc[o4][tau][0], 0.f);
            acc[o4][tau][1] = fmaxf(acc[o4][tau][1], 0.f);
            acc[o4][tau][2] = fmaxf(acc[o4][tau][2], 0.f);
            acc[o4][tau][3] = fmaxf(acc[o4][tau][3], 0.f);
        }
    // BN stats
    int sid = (blockIdx.x & (NSHADOW - 1)) * 128;
    #pragma unroll
    for (int o4 = 0; o4 < 4; ++o4)
        #pragma unroll
        for (int r = 0; r < 4; ++r) {
            float x0 = acc[o4][0][r], x1 = acc[o4][1][r];
            float sv = x0 + x1;
            float ssv = x0 * x0 + x1 * x1;
            sv += __shfl_xor(sv, 1);  ssv += __shfl_xor(ssv, 1);
            sv += __shfl_xor(sv, 2);  ssv += __shfl_xor(ssv, 2);
            sv += __shfl_xor(sv, 4);  ssv += __shfl_xor(ssv, 4);
            sv += __shfl_xor(sv, 8);  ssv += __shfl_xor(ssv, 8);
            if ((t & 15) == o4 * 4 + r) {
                int ch = o4 * 16 + (t >> 4) * 4 + r;
                atomicAdd(&shadow[sid + ch], sv);
                atomicAdd(&shadow[sid + 64 + ch], ssv);
            }
        }
    // pack z into zbuf, coalesced fp8 uint2 stores
    #pragma unroll
    for (int o4 = 0; o4 < 4; ++o4)
        #pragma unroll
        for (int tau = 0; tau < 2; ++tau) {
            uint* p = (uint*)&zbuf[(w * 32 + tau * 16 + (t & 15)) * ZSTRIDE + o4 * 16 + (t >> 4) * 4];
            p[0] = pack2(acc[o4][tau][0], acc[o4][tau][1]);
            p[1] = pack2(acc[o4][tau][2], acc[o4][tau][3]);
        }
    #pragma unroll
    for (int i = 0; i < 4; ++i) {
        uint4 pk = *(const uint4*)&zbuf[(w * 32 + i * 8 + (t >> 3)) * ZSTRIDE + (t & 7) * 8];
        ((uint2*)(zout8 + (size_t)(n0 + i) * ROW))[t] = pkfp8(pk);
    }
}

// load a PAIR of neighbor rows with one wave instruction:
// lanes 0-31 -> row at idx[jj], lanes 32-63 -> row at idx[jj+1]; 16B per lane.
#define PAIRLD(rr, jj) do { \
    int nb_l = __builtin_amdgcn_readlane(idx, (jj)); \
    int nb_h = __builtin_amdgcn_readlane(idx, (jj) + 1); \
    int nb_ = hi ? nb_h : nb_l; \
    rr = ((const uint4*)(zprev8 + (size_t)nb_ * ROW))[q]; \
} while (0)

#define ACC16(rr) do { \
    f32x2 p_; \
    p_ = __builtin_amdgcn_cvt_pk_f32_fp8((int)rr.x, false); s0  += p_.x; s1  += p_.y; \
    p_ = __builtin_amdgcn_cvt_pk_f32_fp8((int)rr.x, true);  s2  += p_.x; s3  += p_.y; \
    p_ = __builtin_amdgcn_cvt_pk_f32_fp8((int)rr.y, false); s4  += p_.x; s5  += p_.y; \
    p_ = __builtin_amdgcn_cvt_pk_f32_fp8((int)rr.y, true);  s6  += p_.x; s7  += p_.y; \
    p_ = __builtin_amdgcn_cvt_pk_f32_fp8((int)rr.z, false); s8  += p_.x; s9  += p_.y; \
    p_ = __builtin_amdgcn_cvt_pk_f32_fp8((int)rr.z, true);  s10 += p_.x; s11 += p_.y; \
    p_ = __builtin_amdgcn_cvt_pk_f32_fp8((int)rr.w, false); s12 += p_.x; s13 += p_.y; \
    p_ = __builtin_amdgcn_cvt_pk_f32_fp8((int)rr.w, true);  s14 += p_.x; s15 += p_.y; \
} while (0)

// ---------------- fused layer (1..4): 1-wave block, 4 nodes; mult-4-padded gather (pads->self,
// self scaled by 1+dg-pdg); mixed 16/8/4-row rounds (up to 8 pair-loads in flight); MFMA MLP.
// last=1 (layer 4): skip z-store, accumulate pool sums directly from registers (k_pool fused away)
__global__ __launch_bounds__(64) __attribute__((amdgpu_waves_per_eu(2, 4)))
void k_layer(const uchar* __restrict__ zprev8,
             const float* __restrict__ shadow_prev,
             const float* __restrict__ gammaP, const float* __restrict__ betaP,
             const int* __restrict__ offs, const int* __restrict__ deg,
             const int* __restrict__ esrc,
             const uint4* __restrict__ w1f, const float* __restrict__ B1,
             const uint4* __restrict__ w2f, const float* __restrict__ B2,
             uchar* __restrict__ zout8, float* __restrict__ shadow,
             float* __restrict__ poolOut, int last) {
    __shared__ __align__(16) ushort zbuf[32 * ZSTRIDE];
    __shared__ __align__(16) float abl[128];
    int t = threadIdx.x;     // 0..63 (single wave)
    int n0 = blockIdx.x * 4;
    int q = t & 31;          // 16B chunk within row
    int hi = t >> 5;         // half-wave: 0 -> even row of pair, 1 -> odd
    // ---- hoist per-node metadata, neighbor-index vectors, self rows (one overlapped latency batch)
    int offv[4], dgv[4], pdgv[4], idxv[4];
    uint2 selfv[4];
    #pragma unroll
    for (int i = 0; i < 4; ++i) {
        offv[i] = offs[n0 + i];
        dgv[i] = deg[n0 + i];
        pdgv[i] = (dgv[i] + 3) & ~3;
    }
    #pragma unroll
    for (int i = 0; i < 4; ++i) idxv[i] = (t < pdgv[i]) ? esrc[offv[i] + t] : 0;
    #pragma unroll
    for (int i = 0; i < 4; ++i) selfv[i] = ((const uint2*)(zprev8 + (size_t)(n0 + i) * ROW))[q * 2 + hi];
    // ---- BN finalize of previous layer: one channel per thread
    {
        float s = 0.f, ss = 0.f;
        #pragma unroll
        for (int j = 0; j < NSHADOW; ++j) {
            s  += shadow_prev[j * 128 + t];
            ss += shadow_prev[j * 128 + 64 + t];
        }
        float mean = s * (1.f / NM);
        float var = ss * (1.f / NM) - mean * mean;
        float a = gammaP[t] * rsqrtf(var + 1e-5f);
        abl[t] = a;
        abl[64 + t] = betaP[t] - mean * a;
    }
    __syncthreads();
    const float4* abp = (const float4*)abl;
    // ---- gather 4 nodes: mixed rounds of 16/8/4 rows (8/4/2 pair-loads in flight)
    #pragma unroll
    for (int i = 0; i < 4; ++i) {
        int off = offv[i], dg = dgv[i], pdg = pdgv[i];
        float s0 = 0.f, s1 = 0.f, s2 = 0.f, s3 = 0.f, s4 = 0.f, s5 = 0.f, s6 = 0.f, s7 = 0.f;
        float s8 = 0.f, s9 = 0.f, s10 = 0.f, s11 = 0.f, s12 = 0.f, s13 = 0.f, s14 = 0.f, s15 = 0.f;
        for (int base = 0; base < pdg; base += 64) {
            int cnt = pdg - base; if (cnt > 64) cnt = 64;     // multiple of 4
            int idx = base ? ((t < cnt) ? esrc[off + base + t] : 0) : idxv[i];
            int j = 0;
            for (; j + 16 <= cnt; j += 16) {
                uint4 r0, r1, r2, r3, r4, r5, r6, r7;
                PAIRLD(r0, j);      PAIRLD(r1, j + 2);  PAIRLD(r2, j + 4);  PAIRLD(r3, j + 6);
                PAIRLD(r4, j + 8);  PAIRLD(r5, j + 10); PAIRLD(r6, j + 12); PAIRLD(r7, j + 14);
                ACC16(r0); ACC16(r1); ACC16(r2); ACC16(r3);
                ACC16(r4); ACC16(r5); ACC16(r6); ACC16(r7);
            }
            if (cnt - j >= 8) {
                uint4 r0, r1, r2, r3;
                PAIRLD(r0, j); PAIRLD(r1, j + 2); PAIRLD(r2, j + 4); PAIRLD(r3, j + 6);
                ACC16(r0); ACC16(r1); ACC16(r2); ACC16(r3);
                j += 8;
            }
            if (cnt - j >= 4) {
                uint4 r0, r1;
                PAIRLD(r0, j); PAIRLD(r1, j + 2);
                ACC16(r0); ACC16(r1);
            }
        }
        // combine half-wave partial sums: each lane keeps its 8 bytes (q*16 + hi*8 ..)
        float u, r0, r1, r2, r3, r4, r5, r6, r7;
        u = hi ? s0 : s8;   r0 = (hi ? s8  : s0) + __shfl_xor(u, 32);
        u = hi ? s1 : s9;   r1 = (hi ? s9  : s1) + __shfl_xor(u, 32);
        u = hi ? s2 : s10;  r2 = (hi ? s10 : s2) + __shfl_xor(u, 32);
        u = hi ? s3 : s11;  r3 = (hi ? s11 : s3) + __shfl_xor(u, 32);
        u = hi ? s4 : s12;  r4 = (hi ? s12 : s4) + __shfl_xor(u, 32);
        u = hi ? s5 : s13;  r5 = (hi ? s13 : s5) + __shfl_xor(u, 32);
        u = hi ? s6 : s14;  r6 = (hi ? s14 : s6) + __shfl_xor(u, 32);
        u = hi ? s7 : s15;  r7 = (hi ? s15 : s7) + __shfl_xor(u, 32);
        // self row: coefficient 1 + dg - pdg compensates the pad slots that point at self
        {
            uint2 sv = selfv[i];
            float cf = (float)(1 + dg - pdg);
            f32x2 p_;
            p_ = __builtin_amdgcn_cvt_pk_f32_fp8((int)sv.x, false); r0 = fmaf(cf, p_.x, r0); r1 = fmaf(cf, p_.y, r1);
            p_ = __builtin_amdgcn_cvt_pk_f32_fp8((int)sv.x, true);  r2 = fmaf(cf, p_.x, r2); r3 = fmaf(cf, p_.y, r3);
            p_ = __builtin_amdgcn_cvt_pk_f32_fp8((int)sv.y, false); r4 = fmaf(cf, p_.x, r4); r5 = fmaf(cf, p_.y, r5);
            p_ = __builtin_amdgcn_cvt_pk_f32_fp8((int)sv.y, true);  r6 = fmaf(cf, p_.x, r6); r7 = fmaf(cf, p_.y, r7);
        }
        // affine (folded BN of prev layer) + pack to zbuf
        int c4 = (q & 3) * 4 + hi * 2;          // float4 index: channel c0 = (q&3)*16 + hi*8
        float4 Af0 = abp[c4], Af1 = abp[c4 + 1];
        float4 Bf0 = abp[16 + c4], Bf1 = abp[16 + c4 + 1];
        float dp1 = (float)(dg + 1);
        uint4 pk;
        pk.x = pack2(fmaf(Af0.x, r0, Bf0.x * dp1), fmaf(Af0.y, r1, Bf0.y * dp1));
        pk.y = pack2(fmaf(Af0.z, r2, Bf0.z * dp1), fmaf(Af0.w, r3, Bf0.w * dp1));
        pk.z = pack2(fmaf(Af1.x, r4, Bf1.x * dp1), fmaf(Af1.y, r5, Bf1.y * dp1));
        pk.w = pack2(fmaf(Af1.z, r6, Bf1.z * dp1), fmaf(Af1.w, r7, Bf1.w * dp1));
        *(uint4*)&zbuf[(i * 8 + (q >> 2)) * ZSTRIDE + (q & 3) * 16 + hi * 8] = pk;
    }
    // ---- MLP via MFMA: D[64 o x 32 nm]; A-frags direct from global (L2-resident)
    bf16x8 bfr[2][2];
    #pragma unroll
    for (int tau = 0; tau < 2; ++tau)
        #pragma unroll
        for (int q2 = 0; q2 < 2; ++q2) {
            U4B8 u;
            u.u = *(const uint4*)&zbuf[(tau * 16 + (t & 15)) * ZSTRIDE + q2 * 32 + (t >> 4) * 8];
            bfr[q2][tau] = u.b;
        }
    f32x4 acc[4][2];
    #pragma unroll
    for (int o4 = 0; o4 < 4; ++o4) {
        float4 bv = *(const float4*)&B1[o4 * 16 + (t >> 4) * 4];
        #pragma unroll
        for (int tau = 0; tau < 2; ++tau) acc[o4][tau] = (f32x4){bv.x, bv.y, bv.z, bv.w};
    }
    #pragma unroll
    for (int o4 = 0; o4 < 4; ++o4)
        #pragma unroll
        for (int q2 = 0; q2 < 2; ++q2) {
            U4B8 a; a.u = w1f[(o4 * 2 + q2) * 64 + t];
            #pragma unroll
            for (int tau = 0; tau < 2; ++tau)
                acc[o4][tau] = __builtin_amdgcn_mfma_f32_16x16x32_bf16(a.b, bfr[q2][tau], acc[o4][tau], 0, 0, 0);
        }
    #pragma unroll
    for (int o4 = 0; o4 < 4; ++o4)
        #pragma unroll
        for (int tau = 0; tau < 2; ++tau) {
            f32x4 v = acc[o4][tau];
            float h0 = fmaxf(v[0], 0.f), h1 = fmaxf(v[1], 0.f), h2 = fmaxf(v[2], 0.f), h3 = fmaxf(v[3], 0.f);
            uint* p = (uint*)&zbuf[(tau * 16 + (t & 15)) * ZSTRIDE + o4 * 16 + (t >> 4) * 4];
            p[0] = pack2(h0, h1); p[1] = pack2(h2, h3);
        }
    #pragma unroll
    for (int tau = 0; tau < 2; ++tau)
        #pragma unroll
        for (int q2 = 0; q2 < 2; ++q2) {
            U4B8 u;
            u.u = *(const uint4*)&zbuf[(tau * 16 + (t & 15)) * ZSTRIDE + q2 * 32 + (t >> 4) * 8];
            bfr[q2][tau] = u.b;
        }
    #pragma unroll
    for (int o4 = 0; o4 < 4; ++o4) {
        float4 bv = *(const float4*)&B2[o4 * 16 + (t >> 4) * 4];
        #pragma unroll
        for (int tau = 0; tau < 2; ++tau) acc[o4][tau] = (f32x4){bv.x, bv.y, bv.z, bv.w};
    }
    #pragma unroll
    for (int o4 = 0; o4 < 4; ++o4)
        #pragma unroll
        for (int q2 = 0; q2 < 2; ++q2) {
            U4B8 a; a.u = w2f[(o4 * 2 + q2) * 64 + t];
            #pragma unroll
            for (int tau = 0; tau < 2; ++tau)
                acc[o4][tau] = __builtin_amdgcn_mfma_f32_16x16x32_bf16(a.b, bfr[q2][tau], acc[o4][tau], 0, 0, 0);
        }
    #pragma unroll
    for (int o4 = 0; o4 < 4; ++o4)
        #pragma unroll
        for (int tau = 0; tau < 2; ++tau) {
            acc[o4][tau][0] = fmaxf(acc[o4][tau][0], 0.f);
            acc[o4][tau][1] = fmaxf(acc[o4][tau][1], 0.f);
            acc[o4][tau][2] = fmaxf(acc[o4][tau][2], 0.f);
            acc[o4][tau][3] = fmaxf(acc[o4][tau][3], 0.f);
        }
    // BN stats: butterfly over 16-lane column group, 2 predicated atomics per matching lane
    int sid = (blockIdx.x & (NSHADOW - 1)) * 128;
    #pragma unroll
    for (int o4 = 0; o4 < 4; ++o4)
        #pragma unroll
        for (int r = 0; r < 4; ++r) {
            float x0 = acc[o4][0][r], x1 = acc[o4][1][r];
            float sv = x0 + x1;
            float ssv = x0 * x0 + x1 * x1;
            sv += __shfl_xor(sv, 1);  ssv += __shfl_xor(ssv, 1);
            sv += __shfl_xor(sv, 2);  ssv += __shfl_xor(ssv, 2);
            sv += __shfl_xor(sv, 4);  ssv += __shfl_xor(ssv, 4);
            sv += __shfl_xor(sv, 8);  ssv += __shfl_xor(ssv, 8);
            if ((t & 15) == o4 * 4 + r) {
                int ch = o4 * 16 + (t >> 4) * 4 + r;
                atomicAdd(&shadow[sid + ch], sv);
                atomicAdd(&shadow[sid + 64 + ch], ssv);
            }
        }
    if (last) {
        // ---- fused pooling: sum over this block's 4 nodes per (m,c); raw z (pre-BN) like k_pool did.
        // acc[o4][tau][r] = z[node = tau*2 + ((t&15)>>3)][m = t&7][c = o4*16 + (t>>4)*4 + r]
        // POOLSH=256 shadow copies: 2.56M atomics spread over 2048 cachelines (~312/line)
        int sidp = (blockIdx.x & (POOLSH - 1)) * 512;
        #pragma unroll
        for (int o4 = 0; o4 < 4; ++o4)
            #pragma unroll
            for (int r = 0; r < 4; ++r) {
                float v = acc[o4][0][r] + acc[o4][1][r];   // sum over tau (2 nodes)
                v += __shfl_xor(v, 8);                     // sum over lane-bit-3 (other 2 nodes)
                if ((t & 8) == 0) {
                    int c = o4 * 16 + (t >> 4) * 4 + r;
                    atomicAdd(&poolOut[sidp + (t & 7) * 64 + c], v);
                }
            }
    } else {
        // pack z2 into zbuf, then coalesced fp8 stores per node
        #pragma unroll
        for (int o4 = 0; o4 < 4; ++o4)
            #pragma unroll
            for (int tau = 0; tau < 2; ++tau) {
                uint* p = (uint*)&zbuf[(tau * 16 + (t & 15)) * ZSTRIDE + o4 * 16 + (t >> 4) * 4];
                p[0] = pack2(acc[o4][tau][0], acc[o4][tau][1]);
                p[1] = pack2(acc[o4][tau][2], acc[o4][tau][3]);
            }
        #pragma unroll
        for (int i = 0; i < 4; ++i) {
            uint4 pk = *(const uint4*)&zbuf[(i * 8 + (t >> 3)) * ZSTRIDE + (t & 7) * 8];
            ((uint2*)(zout8 + (size_t)(n0 + i) * ROW))[t] = pkfp8(pk);
        }
    }
}

// ---------------- head: parallel pool reduction (512 thr, one (m,c) cell each) +
// layer-4 BN finalize + pool-normalize + linear + sigmoid
__global__ __launch_bounds__(512) void k_out(const float* __restrict__ pool, const float* __restrict__ shadow4,
                                             const float* __restrict__ gamma4, const float* __restrict__ beta4,
                                             const float* __restrict__ wout, const float* __restrict__ bout,
                                             float* __restrict__ out) {
    __shared__ float pvs[512];
    __shared__ float abl[128];
    int tid = threadIdx.x;
    // phase 1: each thread sums its (m,c) cell across POOLSH copies (coalesced, 8 waves, ILP8)
    {
        float p0 = 0.f, p1 = 0.f, p2 = 0.f, p3 = 0.f, p4 = 0.f, p5 = 0.f, p6 = 0.f, p7 = 0.f;
        #pragma unroll 4
        for (int j = 0; j < POOLSH; j += 8) {
            p0 += pool[(j + 0) * 512 + tid];
            p1 += pool[(j + 1) * 512 + tid];
            p2 += pool[(j + 2) * 512 + tid];
            p3 += pool[(j + 3) * 512 + tid];
            p4 += pool[(j + 4) * 512 + tid];
            p5 += pool[(j + 5) * 512 + tid];
            p6 += pool[(j + 6) * 512 + tid];
            p7 += pool[(j + 7) * 512 + tid];
        }
        pvs[tid] = ((p0 + p1) + (p2 + p3)) + ((p4 + p5) + (p6 + p7));
    }
    // phase 1b: BN finalize for layer 4 (threads 0..63)
    if (tid < 64) {
        float s = 0.f, ss = 0.f;
        #pragma unroll
        for (int j = 0; j < NSHADOW; ++j) { s += shadow4[j * 128 + tid]; ss += shadow4[j * 128 + 64 + tid]; }
        float mean = s * (1.f / NM);
        float var = ss * (1.f / NM) - mean * mean;
        float a = gamma4[tid] * rsqrtf(var + 1e-5f);
        abl[tid] = a;
        abl[64 + tid] = beta4[tid] - mean * a;
    }
    __syncthreads();
    // phase 2: wave 0 reduces over c per m + sigmoid
    if (tid < 64) {
        int c = tid;
        float a = abl[c], b = abl[64 + c], wv = wout[c];
        for (int m = 0; m < 8; ++m) {
            float v = wv * (a * pvs[m * 64 + c] * (1.f / N_NODES) + b);
            for (int off = 32; off > 0; off >>= 1) v += __shfl_down(v, off);
            if (c == 0) out[m] = 1.f / (1.f + expf(-(v + bout[0])));
        }
    }
}

extern "C" void kernel_launch(void* const* d_in, const int* in_sizes, int n_in,
                              void* d_out, int out_size, void* d_ws, size_t ws_size,
                              hipStream_t stream) {
    const float* x     = (const float*)d_in[0];
    const int*   ei    = (const int*)d_in[1];
    const int*   srcp  = ei;
    const int*   dstp  = ei + N_EDGES;
    const float* w1_0  = (const float*)d_in[3];
    const float* w1    = (const float*)d_in[4];   // [4][64][64]
    const float* b1    = (const float*)d_in[5];   // [5][64]
    const float* w2    = (const float*)d_in[6];   // [5][64][64]
    const float* b2    = (const float*)d_in[7];
    const float* gamma = (const float*)d_in[8];
    const float* beta  = (const float*)d_in[9];
    const float* wout  = (const float*)d_in[10];
    const float* bout  = (const float*)d_in[11];
    float* out = (float*)d_out;

    char* ws = (char*)d_ws;
    size_t off = 0;
    auto alloc = [&](size_t bytes) -> void* {
        void* p = ws + off;
        off = (off + bytes + 255) & ~(size_t)255;
        return p;
    };
    uchar* zA8   = (uchar*)alloc((size_t)N_NODES * ROW);        // 10.25 MB fp8
    uchar* zB8   = (uchar*)alloc((size_t)N_NODES * ROW);
    uint4* wfrag = (uint4*)alloc(4608 * 16);                    // pre-packed A-fragments
    // ---- contiguous zero-initialized span: deg, cursor, shadow[5], pool (POOLSH copies)
    int* deg      = (int*)alloc(N_NODES * 4);
    int* cursor   = (int*)alloc(N_NODES * 4);
    float* shadow = (float*)alloc(5 * NSHADOW * 128 * 4);
    float* pool   = (float*)alloc(POOLSH * 512 * 4);            // 512 KB
    size_t zero_bytes = (size_t)((char*)pool - (char*)deg) + POOLSH * 512 * 4;
    // ---- uninitialized scratch
    int* offs     = (int*)alloc(N_NODES * 4);
    int* esrc     = (int*)alloc(ESRC_CAP * 4);
    int* csum     = (int*)alloc(NCHUNK * 4);
    int* chunkoff = (int*)alloc(NCHUNK * 4);

    hipMemsetAsync(deg, 0, zero_bytes, stream);

    // CSR build (padded, pads->self) + weight pre-pack; merged dispatches
    k_histprep<<<(N_EDGES + 4608 + 255) / 256, 256, 0, stream>>>(dstp, deg, w1, w2, wfrag);
    k_csum<<<NCHUNK, 256, 0, stream>>>(deg, csum);
    k_cscan<<<1, 128, 0, stream>>>(csum, chunkoff);
    k_chunkscan<<<NCHUNK, 256, 0, stream>>>(deg, chunkoff, offs);
    k_fillpad<<<(N_EDGES + N_NODES * 4 + 255) / 256, 256, 0, stream>>>(srcp, dstp, offs, deg, cursor, esrc);

    // layer 0 (MFMA, fp8 output)
    k_layer0<<<N_NODES / 16, 256, 0, stream>>>(x, offs, deg, esrc, w1_0, b1, wfrag + 4096, b2,
                                               zA8, shadow);

    // layers 1..4 fused; ping-pong zA8 <-> zB8 (1-wave blocks, 4 nodes each);
    // layer 4 skips z-store and accumulates pool directly (k_pool fused away)
    const uchar* zin8 = zA8;
    uchar* zo8 = zB8;
    for (int i = 1; i <= 4; ++i) {
        k_layer<<<N_NODES / 4, 64, 0, stream>>>(zin8,
                                                shadow + (size_t)(i - 1) * NSHADOW * 128,
                                                gamma + (i - 1) * 64, beta + (i - 1) * 64,
                                                offs, deg, esrc,
                                                wfrag + (size_t)(i - 1) * 1024, b1 + i * 64,
                                                wfrag + (size_t)(i - 1) * 1024 + 512, b2 + i * 64,
                                                zo8,
                                                shadow + (size_t)i * NSHADOW * 128,
                                                pool, (i == 4) ? 1 : 0);
        const uchar* t8 = zin8; zin8 = zo8; zo8 = (uchar*)t8;
    }

    // head (parallel pool reduction inside)
    k_out<<<1, 512, 0, stream>>>(pool, shadow + 4 * NSHADOW * 128, gamma + 256, beta + 256, wout, bout, out);
}

// Round 12
// 394.089 us; speedup vs baseline: 1.2103x; 1.0317x over previous
//
#include <hip/hip_runtime.h>

#define N_NODES 20000
#define N_EDGES 320000
#define HID 64
#define MDIM 8
#define ROW 512            // HID*MDIM elements per node row (layout: [n][m][c])
#define NM 160000.0f       // N_NODES*MDIM
#define NCHUNK 79          // ceil(20000/256)
#define NSHADOW 16         // shadow copies per layer
#define POOLSH 16          // shadow copies for pooling (131k atomics; memory-side atomic cost is per-op)
#define ZSTRIDE 72         // shorts per nm-row (64 + 8 pad)
#define ESRC_CAP 400000    // padded CSR capacity: 320000 + 20000*4 (pad to mult-of-4)

typedef unsigned int uint;
typedef unsigned char uchar;
typedef unsigned short ushort;
typedef __attribute__((ext_vector_type(8))) short bf16x8;
typedef __attribute__((ext_vector_type(4))) float f32x4;
typedef __attribute__((ext_vector_type(2))) float f32x2;

union U4B8 { uint4 u; bf16x8 b; };

__device__ __forceinline__ float bflo(uint u) { return __uint_as_float(u << 16); }
__device__ __forceinline__ float bfhi(uint u) { return __uint_as_float(u & 0xffff0000u); }
__device__ __forceinline__ uint f2bf(float f) {   // round-to-nearest-even
    uint u = __float_as_uint(f);
    return (u + 0x7fffu + ((u >> 16) & 1u)) >> 16;
}
__device__ __forceinline__ uint pack2(float lo, float hi) { return f2bf(lo) | (f2bf(hi) << 16); }
// pack 8 floats (from a bf16x8-packed uint4) into 8 fp8-e4m3 bytes
__device__ __forceinline__ uint2 pkfp8(uint4 pk) {
    int lo = 0, hi = 0;
    lo = __builtin_amdgcn_cvt_pk_fp8_f32(bflo(pk.x), bfhi(pk.x), lo, false);
    lo = __builtin_amdgcn_cvt_pk_fp8_f32(bflo(pk.y), bfhi(pk.y), lo, true);
    hi = __builtin_amdgcn_cvt_pk_fp8_f32(bflo(pk.z), bfhi(pk.z), hi, false);
    hi = __builtin_amdgcn_cvt_pk_fp8_f32(bflo(pk.w), bfhi(pk.w), hi, true);
    uint2 r; r.x = (uint)lo; r.y = (uint)hi; return r;
}

// ---------------- CSR build (padded to multiple-of-4 per node, pads point at SELF) ------------
// merged: edge histogram + weight pre-pack (independent index ranges, one dispatch)
__global__ __launch_bounds__(256) void k_histprep(const int* __restrict__ dst, int* __restrict__ deg,
                                                  const float* __restrict__ w1, const float* __restrict__ w2,
                                                  uint4* __restrict__ wfrag) {
    int id = blockIdx.x * 256 + threadIdx.x;
    if (id < N_EDGES) { atomicAdd(&deg[dst[id]], 1); return; }
    int pid = id - N_EDGES;                 // weight pre-pack: 4608 ids
    if (pid >= 4608) return;
    const float* W;
    int s;
    if (pid < 4096) {
        int layer = pid >> 10;          // 0..3 -> model layer layer+1
        int rem = pid & 1023;
        int which = rem >> 9;           // 0: w1, 1: w2
        s = rem & 511;
        W = which ? &w2[(size_t)(layer + 1) * 4096] : &w1[(size_t)layer * 4096];
    } else {
        s = pid - 4096;
        W = w2;                         // layer-0 w2
    }
    int f = s >> 6, l = s & 63;
    int o = (f >> 1) * 16 + (l & 15);
    int c0 = (f & 1) * 32 + (l >> 4) * 8;
    const float* p = &W[o * 64 + c0];
    uint4 a;
    a.x = pack2(p[0], p[1]); a.y = pack2(p[2], p[3]);
    a.z = pack2(p[4], p[5]); a.w = pack2(p[6], p[7]);
    wfrag[pid] = a;
}

__global__ __launch_bounds__(256) void k_csum(const int* __restrict__ deg, int* __restrict__ csum) {
    __shared__ int r[256];
    int t = threadIdx.x, i = blockIdx.x * 256 + t;
    r[t] = (i < N_NODES) ? ((deg[i] + 3) & ~3) : 0;
    __syncthreads();
    for (int s = 128; s > 0; s >>= 1) { if (t < s) r[t] += r[t + s]; __syncthreads(); }
    if (t == 0) csum[blockIdx.x] = r[0];
}

__global__ __launch_bounds__(128) void k_cscan(const int* __restrict__ csum, int* __restrict__ chunkoff) {
    __shared__ int s[128];
    int t = threadIdx.x;
    s[t] = (t < NCHUNK) ? csum[t] : 0;
    __syncthreads();
    if (t == 0) { int run = 0; for (int j = 0; j < NCHUNK; ++j) { int x = s[j]; s[j] = run; run += x; } }
    __syncthreads();
    if (t < NCHUNK) chunkoff[t] = s[t];
}

__global__ __launch_bounds__(256) void k_chunkscan(const int* __restrict__ deg, const int* __restrict__ chunkoff,
                                                   int* __restrict__ offs) {
    __shared__ int sd[256];
    int t = threadIdx.x, i = blockIdx.x * 256 + t;
    int v = (i < N_NODES) ? ((deg[i] + 3) & ~3) : 0;
    sd[t] = v;
    __syncthreads();
    for (int off = 1; off < 256; off <<= 1) {
        int x = (t >= off) ? sd[t - off] : 0;
        __syncthreads();
        sd[t] += x;
        __syncthreads();
    }
    if (i < N_NODES) offs[i] = sd[t] - v + chunkoff[blockIdx.x];
}

// merged: CSR fill (per-edge) + padding-slot fill (per-node x4, pads point at SELF node)
__global__ __launch_bounds__(256) void k_fillpad(const int* __restrict__ src, const int* __restrict__ dst,
                                                 const int* __restrict__ offs, const int* __restrict__ deg,
                                                 int* __restrict__ cursor, int* __restrict__ esrc) {
    int id = blockIdx.x * 256 + threadIdx.x;
    if (id < N_EDGES) {
        int d = dst[id];
        int p = atomicAdd(&cursor[d], 1);
        esrc[offs[d] + p] = src[id];
        return;
    }
    int pid = id - N_EDGES;                 // padding: N_NODES*4 ids
    if (pid >= N_NODES * 4) return;
    int n = pid >> 2, s = pid & 3;
    int dg = deg[n], pdg = (dg + 3) & ~3;
    int p = dg + s;
    if (p < pdg) esrc[offs[n] + p] = n;     // pad -> self; k_layer scales self by (1+dg-pdg)
}

// ---------------- fused layer 0 (MFMA): gather x (C=1) + rank-1 linear1 in B-frag regs + MFMA linear2
// block = 4 waves x 4 nodes; neighbor indices preloaded + shfl-broadcast (1 dependent load/round)
__global__ __launch_bounds__(256) void k_layer0(const float* __restrict__ x, const int* __restrict__ offs,
                                                const int* __restrict__ deg, const int* __restrict__ esrc,
                                                const float* __restrict__ W10, const float* __restrict__ B1,
                                                const uint4* __restrict__ w2f0, const float* __restrict__ B2,
                                                uchar* __restrict__ zout8, float* __restrict__ shadow) {
    __shared__ uint4 w2s[512];
    __shared__ __align__(16) ushort zbuf[128 * ZSTRIDE];
    int tid = threadIdx.x;
    for (int s2 = tid; s2 < 512; s2 += 256) w2s[s2] = w2f0[s2];
    __syncthreads();
    int w = tid >> 6, t = tid & 63;
    int n0 = blockIdx.x * 16 + w * 4;
    int g = t >> 3, m = t & 7;
    // ---- hoist per-node metadata + neighbor-index vectors (slots 0..63)
    int offv[4], dgv[4], idxv[4];
    #pragma unroll
    for (int i = 0; i < 4; ++i) { offv[i] = offs[n0 + i]; dgv[i] = deg[n0 + i]; }
    #pragma unroll
    for (int i = 0; i < 4; ++i) idxv[i] = (t < dgv[i]) ? esrc[offv[i] + t] : 0;
    // ---- gather zin0 for 4 nodes: 8 neighbor-slots x 8 m per round (idx via shfl) + xor-butterfly
    float zin0v[4];
    #pragma unroll
    for (int i = 0; i < 4; ++i) {
        int n = n0 + i;
        int dg = dgv[i];
        float acc = (t < 8) ? x[n * 8 + t] : 0.f;
        int dgc = dg < 64 ? dg : 64;
        for (int base = 0; base < dgc; base += 8) {
            int slot = base + g;
            int nb = __shfl(idxv[i], slot & 63);
            float v = 0.f;
            if (slot < dg) v = x[(size_t)nb * 8 + m];
            acc += v;
        }
        for (int k = 64 + g; k < dg; k += 8) {     // cold path (deg > 64: never for this data)
            int nb = esrc[offv[i] + k];
            acc += x[(size_t)nb * 8 + m];
        }
        acc += __shfl_xor(acc, 8);
        acc += __shfl_xor(acc, 16);
        acc += __shfl_xor(acc, 32);   // all lanes: zin0[node i][m = t&7]
        zin0v[i] = acc;
    }
    // ---- h = relu(w10*zin0 + b1) built directly in B-frag layout
    bf16x8 bfr[2][2];
    #pragma unroll
    for (int q2 = 0; q2 < 2; ++q2) {
        int kb = q2 * 32 + (t >> 4) * 8;
        float4 wA = *(const float4*)&W10[kb];
        float4 wB = *(const float4*)&W10[kb + 4];
        float4 bA = *(const float4*)&B1[kb];
        float4 bB = *(const float4*)&B1[kb + 4];
        #pragma unroll
        for (int tau = 0; tau < 2; ++tau) {
            float zv = zin0v[tau * 2 + ((t & 15) >> 3)];
            U4B8 u;
            u.u.x = pack2(fmaxf(fmaf(wA.x, zv, bA.x), 0.f), fmaxf(fmaf(wA.y, zv, bA.y), 0.f));
            u.u.y = pack2(fmaxf(fmaf(wA.z, zv, bA.z), 0.f), fmaxf(fmaf(wA.w, zv, bA.w), 0.f));
            u.u.z = pack2(fmaxf(fmaf(wB.x, zv, bB.x), 0.f), fmaxf(fmaf(wB.y, zv, bB.y), 0.f));
            u.u.w = pack2(fmaxf(fmaf(wB.z, zv, bB.z), 0.f), fmaxf(fmaf(wB.w, zv, bB.w), 0.f));
            bfr[q2][tau] = u.b;
        }
    }
    // ---- linear2 via MFMA
    f32x4 acc[4][2];
    #pragma unroll
    for (int o4 = 0; o4 < 4; ++o4) {
        float4 bv = *(const float4*)&B2[o4 * 16 + (t >> 4) * 4];
        #pragma unroll
        for (int tau = 0; tau < 2; ++tau) acc[o4][tau] = (f32x4){bv.x, bv.y, bv.z, bv.w};
    }
    #pragma unroll
    for (int o4 = 0; o4 < 4; ++o4)
        #pragma unroll
        for (int q2 = 0; q2 < 2; ++q2) {
            U4B8 a; a.u = w2s[(o4 * 2 + q2) * 64 + t];
            #pragma unroll
            for (int tau = 0; tau < 2; ++tau)
                acc[o4][tau] = __builtin_amdgcn_mfma_f32_16x16x32_bf16(a.b, bfr[q2][tau], acc[o4][tau], 0, 0, 0);
        }
    #pragma unroll
    for (int o4 = 0; o4 < 4; ++o4)
        #pragma unroll
        for (int tau = 0; tau < 2; ++tau) {
            acc[o4][tau][0] = fmaxf(acc[o4][tau][0], 0.f);
            acc[o4][tau][1] = fmaxf(acc[o4][tau][1], 0.f);
            acc[o4][tau][2] = fmaxf(acc[o4][tau][2], 0.f);
            acc[o4][tau][3] = fmaxf(acc[o4][tau][3], 0.f);
        }
    // BN stats
    int sid = (blockIdx.x & (NSHADOW - 1)) * 128;
    #pragma unroll
    for (int o4 = 0; o4 < 4; ++o4)
        #pragma unroll
        for (int r = 0; r < 4; ++r) {
            float x0 = acc[o4][0][r], x1 = acc[o4][1][r];
            float sv = x0 + x1;
            float ssv = x0 * x0 + x1 * x1;
            sv += __shfl_xor(sv, 1);  ssv += __shfl_xor(ssv, 1);
            sv += __shfl_xor(sv, 2);  ssv += __shfl_xor(ssv, 2);
            sv += __shfl_xor(sv, 4);  ssv += __shfl_xor(ssv, 4);
            sv += __shfl_xor(sv, 8);  ssv += __shfl_xor(ssv, 8);
            if ((t & 15) == o4 * 4 + r) {
                int ch = o4 * 16 + (t >> 4) * 4 + r;
                atomicAdd(&shadow[sid + ch], sv);
                atomicAdd(&shadow[sid + 64 + ch], ssv);
            }
        }
    // pack z into zbuf, coalesced fp8 uint2 stores
    #pragma unroll
    for (int o4 = 0; o4 < 4; ++o4)
        #pragma unroll
        for (int tau = 0; tau < 2; ++tau) {
            uint* p = (uint*)&zbuf[(w * 32 + tau * 16 + (t & 15)) * ZSTRIDE + o4 * 16 + (t >> 4) * 4];
            p[0] = pack2(acc[o4][tau][0], acc[o4][tau][1]);
            p[1] = pack2(acc[o4][tau][2], acc[o4][tau][3]);
        }
    #pragma unroll
    for (int i = 0; i < 4; ++i) {
        uint4 pk = *(const uint4*)&zbuf[(w * 32 + i * 8 + (t >> 3)) * ZSTRIDE + (t & 7) * 8];
        ((uint2*)(zout8 + (size_t)(n0 + i) * ROW))[t] = pkfp8(pk);
    }
}

// load a PAIR of neighbor rows with one wave instruction:
// lanes 0-31 -> row at idx[jj], lanes 32-63 -> row at idx[jj+1]; 16B per lane.
#define PAIRLD(rr, jj) do { \
    int nb_l = __builtin_amdgcn_readlane(idx, (jj)); \
    int nb_h = __builtin_amdgcn_readlane(idx, (jj) + 1); \
    int nb_ = hi ? nb_h : nb_l; \
    rr = ((const uint4*)(zprev8 + (size_t)nb_ * ROW))[q]; \
} while (0)

#define ACC16(rr) do { \
    f32x2 p_; \
    p_ = __builtin_amdgcn_cvt_pk_f32_fp8((int)rr.x, false); s0  += p_.x; s1  += p_.y; \
    p_ = __builtin_amdgcn_cvt_pk_f32_fp8((int)rr.x, true);  s2  += p_.x; s3  += p_.y; \
    p_ = __builtin_amdgcn_cvt_pk_f32_fp8((int)rr.y, false); s4  += p_.x; s5  += p_.y; \
    p_ = __builtin_amdgcn_cvt_pk_f32_fp8((int)rr.y, true);  s6  += p_.x; s7  += p_.y; \
    p_ = __builtin_amdgcn_cvt_pk_f32_fp8((int)rr.z, false); s8  += p_.x; s9  += p_.y; \
    p_ = __builtin_amdgcn_cvt_pk_f32_fp8((int)rr.z, true);  s10 += p_.x; s11 += p_.y; \
    p_ = __builtin_amdgcn_cvt_pk_f32_fp8((int)rr.w, false); s12 += p_.x; s13 += p_.y; \
    p_ = __builtin_amdgcn_cvt_pk_f32_fp8((int)rr.w, true);  s14 += p_.x; s15 += p_.y; \
} while (0)

// ---------------- fused layer (1..4): 1-wave block, 4 nodes; mult-4-padded gather (pads->self,
// self scaled by 1+dg-pdg); mixed 16/8/4-row rounds (up to 8 pair-loads in flight); MFMA MLP
__global__ __launch_bounds__(64) __attribute__((amdgpu_waves_per_eu(2, 4)))
void k_layer(const uchar* __restrict__ zprev8,
             const float* __restrict__ shadow_prev,
             const float* __restrict__ gammaP, const float* __restrict__ betaP,
             const int* __restrict__ offs, const int* __restrict__ deg,
             const int* __restrict__ esrc,
             const uint4* __restrict__ w1f, const float* __restrict__ B1,
             const uint4* __restrict__ w2f, const float* __restrict__ B2,
             uchar* __restrict__ zout8, float* __restrict__ shadow) {
    __shared__ __align__(16) ushort zbuf[32 * ZSTRIDE];
    __shared__ __align__(16) float abl[128];
    int t = threadIdx.x;     // 0..63 (single wave)
    int n0 = blockIdx.x * 4;
    int q = t & 31;          // 16B chunk within row
    int hi = t >> 5;         // half-wave: 0 -> even row of pair, 1 -> odd
    // ---- hoist per-node metadata, neighbor-index vectors, self rows (one overlapped latency batch)
    int offv[4], dgv[4], pdgv[4], idxv[4];
    uint2 selfv[4];
    #pragma unroll
    for (int i = 0; i < 4; ++i) {
        offv[i] = offs[n0 + i];
        dgv[i] = deg[n0 + i];
        pdgv[i] = (dgv[i] + 3) & ~3;
    }
    #pragma unroll
    for (int i = 0; i < 4; ++i) idxv[i] = (t < pdgv[i]) ? esrc[offv[i] + t] : 0;
    #pragma unroll
    for (int i = 0; i < 4; ++i) selfv[i] = ((const uint2*)(zprev8 + (size_t)(n0 + i) * ROW))[q * 2 + hi];
    // ---- BN finalize of previous layer: one channel per thread
    {
        float s = 0.f, ss = 0.f;
        #pragma unroll
        for (int j = 0; j < NSHADOW; ++j) {
            s  += shadow_prev[j * 128 + t];
            ss += shadow_prev[j * 128 + 64 + t];
        }
        float mean = s * (1.f / NM);
        float var = ss * (1.f / NM) - mean * mean;
        float a = gammaP[t] * rsqrtf(var + 1e-5f);
        abl[t] = a;
        abl[64 + t] = betaP[t] - mean * a;
    }
    __syncthreads();
    const float4* abp = (const float4*)abl;
    // ---- gather 4 nodes: mixed rounds of 16/8/4 rows (8/4/2 pair-loads in flight)
    #pragma unroll
    for (int i = 0; i < 4; ++i) {
        int off = offv[i], dg = dgv[i], pdg = pdgv[i];
        float s0 = 0.f, s1 = 0.f, s2 = 0.f, s3 = 0.f, s4 = 0.f, s5 = 0.f, s6 = 0.f, s7 = 0.f;
        float s8 = 0.f, s9 = 0.f, s10 = 0.f, s11 = 0.f, s12 = 0.f, s13 = 0.f, s14 = 0.f, s15 = 0.f;
        for (int base = 0; base < pdg; base += 64) {
            int cnt = pdg - base; if (cnt > 64) cnt = 64;     // multiple of 4
            int idx = base ? ((t < cnt) ? esrc[off + base + t] : 0) : idxv[i];
            int j = 0;
            for (; j + 16 <= cnt; j += 16) {
                uint4 r0, r1, r2, r3, r4, r5, r6, r7;
                PAIRLD(r0, j);      PAIRLD(r1, j + 2);  PAIRLD(r2, j + 4);  PAIRLD(r3, j + 6);
                PAIRLD(r4, j + 8);  PAIRLD(r5, j + 10); PAIRLD(r6, j + 12); PAIRLD(r7, j + 14);
                ACC16(r0); ACC16(r1); ACC16(r2); ACC16(r3);
                ACC16(r4); ACC16(r5); ACC16(r6); ACC16(r7);
            }
            if (cnt - j >= 8) {
                uint4 r0, r1, r2, r3;
                PAIRLD(r0, j); PAIRLD(r1, j + 2); PAIRLD(r2, j + 4); PAIRLD(r3, j + 6);
                ACC16(r0); ACC16(r1); ACC16(r2); ACC16(r3);
                j += 8;
            }
            if (cnt - j >= 4) {
                uint4 r0, r1;
                PAIRLD(r0, j); PAIRLD(r1, j + 2);
                ACC16(r0); ACC16(r1);
            }
        }
        // combine half-wave partial sums: each lane keeps its 8 bytes (q*16 + hi*8 ..)
        float u, r0, r1, r2, r3, r4, r5, r6, r7;
        u = hi ? s0 : s8;   r0 = (hi ? s8  : s0) + __shfl_xor(u, 32);
        u = hi ? s1 : s9;   r1 = (hi ? s9  : s1) + __shfl_xor(u, 32);
        u = hi ? s2 : s10;  r2 = (hi ? s10 : s2) + __shfl_xor(u, 32);
        u = hi ? s3 : s11;  r3 = (hi ? s11 : s3) + __shfl_xor(u, 32);
        u = hi ? s4 : s12;  r4 = (hi ? s12 : s4) + __shfl_xor(u, 32);
        u = hi ? s5 : s13;  r5 = (hi ? s13 : s5) + __shfl_xor(u, 32);
        u = hi ? s6 : s14;  r6 = (hi ? s14 : s6) + __shfl_xor(u, 32);
        u = hi ? s7 : s15;  r7 = (hi ? s15 : s7) + __shfl_xor(u, 32);
        // self row: coefficient 1 + dg - pdg compensates the pad slots that point at self
        {
            uint2 sv = selfv[i];
            float cf = (float)(1 + dg - pdg);
            f32x2 p_;
            p_ = __builtin_amdgcn_cvt_pk_f32_fp8((int)sv.x, false); r0 = fmaf(cf, p_.x, r0); r1 = fmaf(cf, p_.y, r1);
            p_ = __builtin_amdgcn_cvt_pk_f32_fp8((int)sv.x, true);  r2 = fmaf(cf, p_.x, r2); r3 = fmaf(cf, p_.y, r3);
            p_ = __builtin_amdgcn_cvt_pk_f32_fp8((int)sv.y, false); r4 = fmaf(cf, p_.x, r4); r5 = fmaf(cf, p_.y, r5);
            p_ = __builtin_amdgcn_cvt_pk_f32_fp8((int)sv.y, true);  r6 = fmaf(cf, p_.x, r6); r7 = fmaf(cf, p_.y, r7);
        }
        // affine (folded BN of prev layer) + pack to zbuf
        int c4 = (q & 3) * 4 + hi * 2;          // float4 index: channel c0 = (q&3)*16 + hi*8
        float4 Af0 = abp[c4], Af1 = abp[c4 + 1];
        float4 Bf0 = abp[16 + c4], Bf1 = abp[16 + c4 + 1];
        float dp1 = (float)(dg + 1);
        uint4 pk;
        pk.x = pack2(fmaf(Af0.x, r0, Bf0.x * dp1), fmaf(Af0.y, r1, Bf0.y * dp1));
        pk.y = pack2(fmaf(Af0.z, r2, Bf0.z * dp1), fmaf(Af0.w, r3, Bf0.w * dp1));
        pk.z = pack2(fmaf(Af1.x, r4, Bf1.x * dp1), fmaf(Af1.y, r5, Bf1.y * dp1));
        pk.w = pack2(fmaf(Af1.z, r6, Bf1.z * dp1), fmaf(Af1.w, r7, Bf1.w * dp1));
        *(uint4*)&zbuf[(i * 8 + (q >> 2)) * ZSTRIDE + (q & 3) * 16 + hi * 8] = pk;
    }
    // ---- MLP via MFMA: D[64 o x 32 nm]; A-frags direct from global (L2-resident)
    bf16x8 bfr[2][2];
    #pragma unroll
    for (int tau = 0; tau < 2; ++tau)
        #pragma unroll
        for (int q2 = 0; q2 < 2; ++q2) {
            U4B8 u;
            u.u = *(const uint4*)&zbuf[(tau * 16 + (t & 15)) * ZSTRIDE + q2 * 32 + (t >> 4) * 8];
            bfr[q2][tau] = u.b;
        }
    f32x4 acc[4][2];
    #pragma unroll
    for (int o4 = 0; o4 < 4; ++o4) {
        float4 bv = *(const float4*)&B1[o4 * 16 + (t >> 4) * 4];
        #pragma unroll
        for (int tau = 0; tau < 2; ++tau) acc[o4][tau] = (f32x4){bv.x, bv.y, bv.z, bv.w};
    }
    #pragma unroll
    for (int o4 = 0; o4 < 4; ++o4)
        #pragma unroll
        for (int q2 = 0; q2 < 2; ++q2) {
            U4B8 a; a.u = w1f[(o4 * 2 + q2) * 64 + t];
            #pragma unroll
            for (int tau = 0; tau < 2; ++tau)
                acc[o4][tau] = __builtin_amdgcn_mfma_f32_16x16x32_bf16(a.b, bfr[q2][tau], acc[o4][tau], 0, 0, 0);
        }
    #pragma unroll
    for (int o4 = 0; o4 < 4; ++o4)
        #pragma unroll
        for (int tau = 0; tau < 2; ++tau) {
            f32x4 v = acc[o4][tau];
            float h0 = fmaxf(v[0], 0.f), h1 = fmaxf(v[1], 0.f), h2 = fmaxf(v[2], 0.f), h3 = fmaxf(v[3], 0.f);
            uint* p = (uint*)&zbuf[(tau * 16 + (t & 15)) * ZSTRIDE + o4 * 16 + (t >> 4) * 4];
            p[0] = pack2(h0, h1); p[1] = pack2(h2, h3);
        }
    #pragma unroll
    for (int tau = 0; tau < 2; ++tau)
        #pragma unroll
        for (int q2 = 0; q2 < 2; ++q2) {
            U4B8 u;
            u.u = *(const uint4*)&zbuf[(tau * 16 + (t & 15)) * ZSTRIDE + q2 * 32 + (t >> 4) * 8];
            bfr[q2][tau] = u.b;
        }
    #pragma unroll
    for (int o4 = 0; o4 < 4; ++o4) {
        float4 bv = *(const float4*)&B2[o4 * 16 + (t >> 4) * 4];
        #pragma unroll
        for (int tau = 0; tau < 2; ++tau) acc[o4][tau] = (f32x4){bv.x, bv.y, bv.z, bv.w};
    }
    #pragma unroll
    for (int o4 = 0; o4 < 4; ++o4)
        #pragma unroll
        for (int q2 = 0; q2 < 2; ++q2) {
            U4B8 a; a.u = w2f[(o4 * 2 + q2) * 64 + t];
            #pragma unroll
            for (int tau = 0; tau < 2; ++tau)
                acc[o4][tau] = __builtin_amdgcn_mfma_f32_16x16x32_bf16(a.b, bfr[q2][tau], acc[o4][tau], 0, 0, 0);
        }
    #pragma unroll
    for (int o4 = 0; o4 < 4; ++o4)
        #pragma unroll
        for (int tau = 0; tau < 2; ++tau) {
            acc[o4][tau][0] = fmaxf(acc[o4][tau][0], 0.f);
            acc[o4][tau][1] = fmaxf(acc[o4][tau][1], 0.f);
            acc[o4][tau][2] = fmaxf(acc[o4][tau][2], 0.f);
            acc[o4][tau][3] = fmaxf(acc[o4][tau][3], 0.f);
        }
    // BN stats: butterfly over 16-lane column group, 2 predicated atomics per matching lane
    int sid = (blockIdx.x & (NSHADOW - 1)) * 128;
    #pragma unroll
    for (int o4 = 0; o4 < 4; ++o4)
        #pragma unroll
        for (int r = 0; r < 4; ++r) {
            float x0 = acc[o4][0][r], x1 = acc[o4][1][r];
            float sv = x0 + x1;
            float ssv = x0 * x0 + x1 * x1;
            sv += __shfl_xor(sv, 1);  ssv += __shfl_xor(ssv, 1);
            sv += __shfl_xor(sv, 2);  ssv += __shfl_xor(ssv, 2);
            sv += __shfl_xor(sv, 4);  ssv += __shfl_xor(ssv, 4);
            sv += __shfl_xor(sv, 8);  ssv += __shfl_xor(ssv, 8);
            if ((t & 15) == o4 * 4 + r) {
                int ch = o4 * 16 + (t >> 4) * 4 + r;
                atomicAdd(&shadow[sid + ch], sv);
                atomicAdd(&shadow[sid + 64 + ch], ssv);
            }
        }
    // pack z2 into zbuf, then coalesced fp8 stores per node
    #pragma unroll
    for (int o4 = 0; o4 < 4; ++o4)
        #pragma unroll
        for (int tau = 0; tau < 2; ++tau) {
            uint* p = (uint*)&zbuf[(tau * 16 + (t & 15)) * ZSTRIDE + o4 * 16 + (t >> 4) * 4];
            p[0] = pack2(acc[o4][tau][0], acc[o4][tau][1]);
            p[1] = pack2(acc[o4][tau][2], acc[o4][tau][3]);
        }
    #pragma unroll
    for (int i = 0; i < 4; ++i) {
        uint4 pk = *(const uint4*)&zbuf[(i * 8 + (t >> 3)) * ZSTRIDE + (t & 7) * 8];
        ((uint2*)(zout8 + (size_t)(n0 + i) * ROW))[t] = pkfp8(pk);
    }
}

// ---------------- pooling over nodes (fp8 raw z, [n][m][c] rows)
// POOLSH shadow copies kill same-cacheline atomic serialization; 256 blocks -> 131k atomics total
__global__ __launch_bounds__(256) void k_pool(const uint* __restrict__ z8, float* __restrict__ pool) {
    int t = blockIdx.x * 256 + threadIdx.x;            // 65536 threads
    float s0 = 0.f, s1 = 0.f, s2 = 0.f, s3 = 0.f;
    for (int u = t; u < N_NODES * ROW / 4; u += 65536) {
        uint v = z8[u];
        f32x2 p0 = __builtin_amdgcn_cvt_pk_f32_fp8((int)v, false);
        f32x2 p1 = __builtin_amdgcn_cvt_pk_f32_fp8((int)v, true);
        s0 += p0.x; s1 += p0.y; s2 += p1.x; s3 += p1.y;
    }
    int k4 = t & 127;                                   // uint index within a row; elem position = m*64+c
    int sid = (blockIdx.x & (POOLSH - 1)) * 512;
    atomicAdd(&pool[sid + k4 * 4 + 0], s0);
    atomicAdd(&pool[sid + k4 * 4 + 1], s1);
    atomicAdd(&pool[sid + k4 * 4 + 2], s2);
    atomicAdd(&pool[sid + k4 * 4 + 3], s3);
}

// ---------------- head: fold layer-4 BN finalize + pool-normalize + linear + sigmoid
__global__ __launch_bounds__(64) void k_out(const float* __restrict__ pool, const float* __restrict__ shadow4,
                                            const float* __restrict__ gamma4, const float* __restrict__ beta4,
                                            const float* __restrict__ wout, const float* __restrict__ bout,
                                            float* __restrict__ out) {
    int c = threadIdx.x;
    float s = 0.f, ss = 0.f;
    #pragma unroll
    for (int j = 0; j < NSHADOW; ++j) { s += shadow4[j * 128 + c]; ss += shadow4[j * 128 + 64 + c]; }
    float mean = s * (1.f / NM);
    float var = ss * (1.f / NM) - mean * mean;
    float a = gamma4[c] * rsqrtf(var + 1e-5f);
    float b = beta4[c] - mean * a;
    float wv = wout[c];
    for (int m = 0; m < 8; ++m) {
        float pv = 0.f;
        #pragma unroll
        for (int j = 0; j < POOLSH; ++j) pv += pool[j * 512 + m * 64 + c];
        float v = wv * (a * pv * (1.f / N_NODES) + b);
        for (int off = 32; off > 0; off >>= 1) v += __shfl_down(v, off);
        if (c == 0) out[m] = 1.f / (1.f + expf(-(v + bout[0])));
    }
}

extern "C" void kernel_launch(void* const* d_in, const int* in_sizes, int n_in,
                              void* d_out, int out_size, void* d_ws, size_t ws_size,
                              hipStream_t stream) {
    const float* x     = (const float*)d_in[0];
    const int*   ei    = (const int*)d_in[1];
    const int*   srcp  = ei;
    const int*   dstp  = ei + N_EDGES;
    const float* w1_0  = (const float*)d_in[3];
    const float* w1    = (const float*)d_in[4];   // [4][64][64]
    const float* b1    = (const float*)d_in[5];   // [5][64]
    const float* w2    = (const float*)d_in[6];   // [5][64][64]
    const float* b2    = (const float*)d_in[7];
    const float* gamma = (const float*)d_in[8];
    const float* beta  = (const float*)d_in[9];
    const float* wout  = (const float*)d_in[10];
    const float* bout  = (const float*)d_in[11];
    float* out = (float*)d_out;

    char* ws = (char*)d_ws;
    size_t off = 0;
    auto alloc = [&](size_t bytes) -> void* {
        void* p = ws + off;
        off = (off + bytes + 255) & ~(size_t)255;
        return p;
    };
    uchar* zA8   = (uchar*)alloc((size_t)N_NODES * ROW);        // 10.25 MB fp8
    uchar* zB8   = (uchar*)alloc((size_t)N_NODES * ROW);
    uint4* wfrag = (uint4*)alloc(4608 * 16);                    // pre-packed A-fragments
    // ---- contiguous zero-initialized span: deg, cursor, shadow[5], pool (POOLSH copies)
    int* deg      = (int*)alloc(N_NODES * 4);
    int* cursor   = (int*)alloc(N_NODES * 4);
    float* shadow = (float*)alloc(5 * NSHADOW * 128 * 4);
    float* pool   = (float*)alloc(POOLSH * 512 * 4);
    size_t zero_bytes = (size_t)((char*)pool - (char*)deg) + POOLSH * 512 * 4;
    // ---- uninitialized scratch
    int* offs     = (int*)alloc(N_NODES * 4);
    int* esrc     = (int*)alloc(ESRC_CAP * 4);
    int* csum     = (int*)alloc(NCHUNK * 4);
    int* chunkoff = (int*)alloc(NCHUNK * 4);

    hipMemsetAsync(deg, 0, zero_bytes, stream);

    // CSR build (padded, pads->self) + weight pre-pack; merged dispatches
    k_histprep<<<(N_EDGES + 4608 + 255) / 256, 256, 0, stream>>>(dstp, deg, w1, w2, wfrag);
    k_csum<<<NCHUNK, 256, 0, stream>>>(deg, csum);
    k_cscan<<<1, 128, 0, stream>>>(csum, chunkoff);
    k_chunkscan<<<NCHUNK, 256, 0, stream>>>(deg, chunkoff, offs);
    k_fillpad<<<(N_EDGES + N_NODES * 4 + 255) / 256, 256, 0, stream>>>(srcp, dstp, offs, deg, cursor, esrc);

    // layer 0 (MFMA, fp8 output)
    k_layer0<<<N_NODES / 16, 256, 0, stream>>>(x, offs, deg, esrc, w1_0, b1, wfrag + 4096, b2,
                                               zA8, shadow);

    // layers 1..4 fused; ping-pong zA8 <-> zB8 (1-wave blocks, 4 nodes each)
    const uchar* zin8 = zA8;
    uchar* zo8 = zB8;
    for (int i = 1; i <= 4; ++i) {
        k_layer<<<N_NODES / 4, 64, 0, stream>>>(zin8,
                                                shadow + (size_t)(i - 1) * NSHADOW * 128,
                                                gamma + (i - 1) * 64, beta + (i - 1) * 64,
                                                offs, deg, esrc,
                                                wfrag + (size_t)(i - 1) * 1024, b1 + i * 64,
                                                wfrag + (size_t)(i - 1) * 1024 + 512, b2 + i * 64,
                                                zo8,
                                                shadow + (size_t)i * NSHADOW * 128);
        const uchar* t8 = zin8; zin8 = zo8; zo8 = (uchar*)t8;
    }
    // after 4 swaps, final raw z (layer 4) is back in zA8

    // head
    k_pool<<<256, 256, 0, stream>>>((const uint*)zA8, pool);
    k_out<<<1, 64, 0, stream>>>(pool, shadow + 4 * NSHADOW * 128, gamma + 256, beta + 256, wout, bout, out);
}